// Round 1
// baseline (843.939 us; speedup 1.0000x reference)
//
#include <hip/hip_runtime.h>

// GCN: h0 = relu(c_dst ⊙ Agg(c_src ⊙ x @ W0) + b0); h1 = same with W1; out = h1 @ Wc + bc
// Agg via CSR built per-call (histogram -> scan -> counting scatter), no per-feature atomics.

// ---------------- CSR build ----------------

__global__ __launch_bounds__(256) void k_histo(const int* __restrict__ src, const int* __restrict__ dst,
                                               int E, int* __restrict__ dout, int* __restrict__ din) {
  int stride = gridDim.x * blockDim.x;
  for (int e = blockIdx.x * blockDim.x + threadIdx.x; e < E; e += stride) {
    atomicAdd(&dout[src[e]], 1);
    atomicAdd(&din[dst[e]], 1);
  }
}

__global__ __launch_bounds__(256) void k_coeffs(const int* __restrict__ dout, const int* __restrict__ din,
                                                float* __restrict__ c_src, float* __restrict__ c_dst, int N) {
  int i = blockIdx.x * blockDim.x + threadIdx.x;
  if (i < N) {
    c_src[i] = rsqrtf((float)max(dout[i], 1));
    c_dst[i] = rsqrtf((float)max(din[i], 1));
  }
}

// per-block sums of 1024 ints
__global__ __launch_bounds__(256) void k_scan_partial(const int* __restrict__ din, int* __restrict__ bsum, int N) {
  __shared__ int s[256];
  int t = threadIdx.x;
  int base = blockIdx.x * 1024;
  int sum = 0;
#pragma unroll
  for (int j = 0; j < 4; j++) {
    int idx = base + t + j * 256;
    if (idx < N) sum += din[idx];
  }
  s[t] = sum;
  __syncthreads();
  for (int off = 128; off > 0; off >>= 1) {
    if (t < off) s[t] += s[t + off];
    __syncthreads();
  }
  if (t == 0) bsum[blockIdx.x] = s[0];
}

// exclusive scan of <=128 block sums, single block
__global__ __launch_bounds__(128) void k_scan_bsums(int* bsum, int nb) {
  __shared__ int s[128];
  int t = threadIdx.x;
  s[t] = (t < nb) ? bsum[t] : 0;
  __syncthreads();
  for (int off = 1; off < 128; off <<= 1) {
    int v = (t >= off) ? s[t - off] : 0;
    __syncthreads();
    s[t] += v;
    __syncthreads();
  }
  if (t < nb) bsum[t] = (t == 0) ? 0 : s[t - 1];
}

// per-block exclusive scan (4 elems/thread) + block offset -> row_ptr & cursor copy
__global__ __launch_bounds__(256) void k_scan_final(const int* __restrict__ din, const int* __restrict__ bsum,
                                                    int* __restrict__ rp, int* __restrict__ cursor, int N, int E) {
  __shared__ int s[256];
  int t = threadIdx.x;
  int i0 = blockIdx.x * 1024 + t * 4;
  int v0 = 0, v1 = 0, v2 = 0, v3 = 0;
  if (i0 + 3 < N) {
    int4 q = *(const int4*)&din[i0];
    v0 = q.x; v1 = q.y; v2 = q.z; v3 = q.w;
  } else {
    if (i0 + 0 < N) v0 = din[i0 + 0];
    if (i0 + 1 < N) v1 = din[i0 + 1];
    if (i0 + 2 < N) v2 = din[i0 + 2];
    if (i0 + 3 < N) v3 = din[i0 + 3];
  }
  s[t] = v0 + v1 + v2 + v3;
  __syncthreads();
  for (int off = 1; off < 256; off <<= 1) {
    int v = (t >= off) ? s[t - off] : 0;
    __syncthreads();
    s[t] += v;
    __syncthreads();
  }
  int prev = ((t == 0) ? 0 : s[t - 1]) + bsum[blockIdx.x];
  int e0 = prev, e1 = e0 + v0, e2 = e1 + v1, e3 = e2 + v2;
  if (i0 + 3 < N) {
    *(int4*)&rp[i0] = make_int4(e0, e1, e2, e3);
    *(int4*)&cursor[i0] = make_int4(e0, e1, e2, e3);
  } else {
    if (i0 + 0 < N) { rp[i0 + 0] = e0; cursor[i0 + 0] = e0; }
    if (i0 + 1 < N) { rp[i0 + 1] = e1; cursor[i0 + 1] = e1; }
    if (i0 + 2 < N) { rp[i0 + 2] = e2; cursor[i0 + 2] = e2; }
    if (i0 + 3 < N) { rp[i0 + 3] = e3; cursor[i0 + 3] = e3; }
  }
  if (blockIdx.x == 0 && t == 0) rp[N] = E;
}

__global__ __launch_bounds__(256) void k_scatter(const int* __restrict__ src, const int* __restrict__ dst,
                                                 int* __restrict__ cursor, int* __restrict__ ci, int E) {
  int stride = gridDim.x * blockDim.x;
  for (int e = blockIdx.x * blockDim.x + threadIdx.x; e < E; e += stride) {
    int d = dst[e];
    int pos = atomicAdd(&cursor[d], 1);
    ci[pos] = src[e];
  }
}

// ---------------- Dense: out[r][c] = sum_k A[r][k]*scale[r]*W[k][c], K=128, 128 cols ----------------
// 64 rows/block, 256 threads, K chunked by 32. Thread: 4 rows x (4 + 4) cols.

__global__ __launch_bounds__(256) void k_gemm128(const float* __restrict__ A, const float* __restrict__ W,
                                                 const float* __restrict__ scale, float* __restrict__ out, int N) {
  __shared__ float As[64][36];   // +4 pad: rows 4 apart land 2-way (free), not 4-way
  __shared__ float Ws[32][128];
  int t = threadIdx.x;
  int row0 = blockIdx.x * 64;
  int colg = (t & 15) * 4;   // cols colg..+3 and colg+64..+67
  int rowg = (t >> 4) * 4;   // rows rowg..+3

  float acc[4][8];
#pragma unroll
  for (int r = 0; r < 4; r++)
#pragma unroll
    for (int c = 0; c < 8; c++) acc[r][c] = 0.f;

  for (int kb = 0; kb < 128; kb += 32) {
#pragma unroll
    for (int i = 0; i < 2; i++) {
      int f = t + i * 256;         // 0..511 float4 slots of 64x32 tile
      int r = f >> 3;
      int c4 = (f & 7) * 4;
      int g = row0 + r;
      float4 v = make_float4(0.f, 0.f, 0.f, 0.f);
      if (g < N) {
        v = *(const float4*)&A[(size_t)g * 128 + kb + c4];
        float sc = scale[g];
        v.x *= sc; v.y *= sc; v.z *= sc; v.w *= sc;
      }
      *(float4*)&As[r][c4] = v;
    }
#pragma unroll
    for (int i = 0; i < 4; i++) {
      int f = t + i * 256;         // 0..1023 float4 slots of 32x128 tile
      int kr = f >> 5;
      int c4 = (f & 31) * 4;
      *(float4*)&Ws[kr][c4] = *(const float4*)&W[(size_t)(kb + kr) * 128 + c4];
    }
    __syncthreads();
#pragma unroll
    for (int k = 0; k < 32; k++) {
      float4 w0 = *(const float4*)&Ws[k][colg];
      float4 w1 = *(const float4*)&Ws[k][colg + 64];
#pragma unroll
      for (int r = 0; r < 4; r++) {
        float a = As[rowg + r][k];
        acc[r][0] = fmaf(a, w0.x, acc[r][0]);
        acc[r][1] = fmaf(a, w0.y, acc[r][1]);
        acc[r][2] = fmaf(a, w0.z, acc[r][2]);
        acc[r][3] = fmaf(a, w0.w, acc[r][3]);
        acc[r][4] = fmaf(a, w1.x, acc[r][4]);
        acc[r][5] = fmaf(a, w1.y, acc[r][5]);
        acc[r][6] = fmaf(a, w1.z, acc[r][6]);
        acc[r][7] = fmaf(a, w1.w, acc[r][7]);
      }
    }
    __syncthreads();
  }
#pragma unroll
  for (int r = 0; r < 4; r++) {
    int g = row0 + rowg + r;
    if (g < N) {
      *(float4*)&out[(size_t)g * 128 + colg] = make_float4(acc[r][0], acc[r][1], acc[r][2], acc[r][3]);
      *(float4*)&out[(size_t)g * 128 + colg + 64] = make_float4(acc[r][4], acc[r][5], acc[r][6], acc[r][7]);
    }
  }
}

// ---------------- Sparse aggregation: one wave per node, lane = 2 feats ----------------

__global__ __launch_bounds__(256) void k_aggregate(const float* __restrict__ hin, const int* __restrict__ rp,
                                                   const int* __restrict__ ci, const float* __restrict__ c_dst,
                                                   const float* __restrict__ bias, float* __restrict__ hout, int N) {
  int v = blockIdx.x * 4 + (threadIdx.x >> 6);
  if (v >= N) return;
  int lane = (threadIdx.x & 63) * 2;
  int p = rp[v], pe = rp[v + 1];
  float ax = 0.f, ay = 0.f;
  for (; p < pe; ++p) {
    int u = ci[p];
    float2 tv = *(const float2*)&hin[(size_t)u * 128 + lane];
    ax += tv.x;
    ay += tv.y;
  }
  float cd = c_dst[v];
  float2 o;
  o.x = fmaxf(fmaf(ax, cd, bias[lane]), 0.f);
  o.y = fmaxf(fmaf(ay, cd, bias[lane + 1]), 0.f);
  *(float2*)&hout[(size_t)v * 128 + lane] = o;
}

// ---------------- Classifier: out[N,47] = h @ Wc + bc ----------------

__global__ __launch_bounds__(256) void k_classifier(const float* __restrict__ h, const float* __restrict__ Wc,
                                                    const float* __restrict__ bc, float* __restrict__ out, int N) {
  __shared__ float hs[64][128];
  __shared__ float Wct[47][132];  // transposed, padded
  __shared__ float bs[47];
  int t = threadIdx.x;
  int row0 = blockIdx.x * 64;
  for (int f = t; f < 128 * 47; f += 256) {
    int k = f / 47;
    int c = f - k * 47;
    Wct[c][k] = Wc[f];
  }
  if (t < 47) bs[t] = bc[t];
#pragma unroll
  for (int i = 0; i < 8; i++) {
    int f = t + i * 256;           // 2048 float4 slots of 64x128
    int r = f >> 5;
    int c4 = (f & 31) * 4;
    int g = row0 + r;
    float4 v = make_float4(0.f, 0.f, 0.f, 0.f);
    if (g < N) v = *(const float4*)&h[(size_t)g * 128 + c4];
    *(float4*)&hs[r][c4] = v;
  }
  __syncthreads();
  for (int idx = t; idx < 64 * 47; idx += 256) {
    int r = idx / 47;
    int c = idx - r * 47;
    int g = row0 + r;
    float s = 0.f;
#pragma unroll
    for (int k4 = 0; k4 < 128; k4 += 4) {
      float4 a = *(const float4*)&hs[r][k4];
      float4 w = *(const float4*)&Wct[c][k4];
      s = fmaf(a.x, w.x, s);
      s = fmaf(a.y, w.y, s);
      s = fmaf(a.z, w.z, s);
      s = fmaf(a.w, w.w, s);
    }
    if (g < N) out[(size_t)g * 47 + c] = s + bs[c];
  }
}

// ---------------- launch ----------------

extern "C" void kernel_launch(void* const* d_in, const int* in_sizes, int n_in,
                              void* d_out, int out_size, void* d_ws, size_t ws_size,
                              hipStream_t stream) {
  const float* x  = (const float*)d_in[0];
  const int* edges = (const int*)d_in[1];
  const float* W0 = (const float*)d_in[2];
  const float* b0 = (const float*)d_in[3];
  const float* W1 = (const float*)d_in[4];
  const float* b1 = (const float*)d_in[5];
  const float* Wc = (const float*)d_in[6];
  const float* bc = (const float*)d_in[7];
  float* out = (float*)d_out;

  int N = in_sizes[0] / 128;
  int E = in_sizes[1] / 2;
  const int* src = edges;
  const int* dst = edges + E;

  char* base = (char*)d_ws;
  size_t off = 0;
  auto alloc = [&](size_t bytes) -> void* {
    void* p = base + off;
    off += (bytes + 255) & ~(size_t)255;
    return p;
  };
  float* c_src = (float*)alloc((size_t)N * 4);
  float* c_dst = (float*)alloc((size_t)N * 4);
  int* deg = (int*)alloc((size_t)2 * N * 4);   // [deg_out | deg_in]
  int* deg_out = deg;
  int* deg_in = deg + N;
  int* row_ptr = (int*)alloc((size_t)(N + 1) * 4);
  int* cursor = (int*)alloc((size_t)N * 4);
  int* bsum = (int*)alloc(1024 * 4);
  int* col_idx = (int*)alloc((size_t)E * 4);
  float* h0 = (float*)alloc((size_t)N * 128 * 4);
  float* h1 = (float*)alloc((size_t)N * 128 * 4);

  int nb = (N + 1023) / 1024;

  hipMemsetAsync(deg, 0, (size_t)2 * N * 4, stream);
  k_histo<<<1024, 256, 0, stream>>>(src, dst, E, deg_out, deg_in);
  k_coeffs<<<(N + 255) / 256, 256, 0, stream>>>(deg_out, deg_in, c_src, c_dst, N);
  k_scan_partial<<<nb, 256, 0, stream>>>(deg_in, bsum, N);
  k_scan_bsums<<<1, 128, 0, stream>>>(bsum, nb);
  k_scan_final<<<nb, 256, 0, stream>>>(deg_in, bsum, row_ptr, cursor, N, E);
  k_scatter<<<1024, 256, 0, stream>>>(src, dst, cursor, col_idx, E);

  k_gemm128<<<(N + 63) / 64, 256, 0, stream>>>(x, W0, c_src, h0, N);
  k_aggregate<<<(N + 3) / 4, 256, 0, stream>>>(h0, row_ptr, col_idx, c_dst, b0, h1, N);
  k_gemm128<<<(N + 63) / 64, 256, 0, stream>>>(h1, W1, c_src, h0, N);
  k_aggregate<<<(N + 3) / 4, 256, 0, stream>>>(h0, row_ptr, col_idx, c_dst, b1, h1, N);
  k_classifier<<<(N + 63) / 64, 256, 0, stream>>>(h1, Wc, bc, out, N);
}

// Round 2
// 751.105 us; speedup vs baseline: 1.1236x; 1.1236x over previous
//
#include <hip/hip_runtime.h>

// GCN: h0 = relu(c_dst ⊙ Agg(c_src ⊙ x @ W0) + b0); h1 = same with W1; out = h1 @ Wc + bc
// Agg via CSR built per-call (histogram -> scan -> counting scatter), no per-feature atomics.
// R1: aggregate rewritten for MLP — 2 neighbors/wave (half-wave rows, float4/lane) x2 unroll.

// ---------------- CSR build ----------------

__global__ __launch_bounds__(256) void k_histo(const int* __restrict__ src, const int* __restrict__ dst,
                                               int E, int* __restrict__ dout, int* __restrict__ din) {
  int stride = gridDim.x * blockDim.x;
  for (int e = blockIdx.x * blockDim.x + threadIdx.x; e < E; e += stride) {
    atomicAdd(&dout[src[e]], 1);
    atomicAdd(&din[dst[e]], 1);
  }
}

__global__ __launch_bounds__(256) void k_coeffs(const int* __restrict__ dout, const int* __restrict__ din,
                                                float* __restrict__ c_src, float* __restrict__ c_dst, int N) {
  int i = blockIdx.x * blockDim.x + threadIdx.x;
  if (i < N) {
    c_src[i] = rsqrtf((float)max(dout[i], 1));
    c_dst[i] = rsqrtf((float)max(din[i], 1));
  }
}

// per-block sums of 1024 ints
__global__ __launch_bounds__(256) void k_scan_partial(const int* __restrict__ din, int* __restrict__ bsum, int N) {
  __shared__ int s[256];
  int t = threadIdx.x;
  int base = blockIdx.x * 1024;
  int sum = 0;
#pragma unroll
  for (int j = 0; j < 4; j++) {
    int idx = base + t + j * 256;
    if (idx < N) sum += din[idx];
  }
  s[t] = sum;
  __syncthreads();
  for (int off = 128; off > 0; off >>= 1) {
    if (t < off) s[t] += s[t + off];
    __syncthreads();
  }
  if (t == 0) bsum[blockIdx.x] = s[0];
}

// exclusive scan of <=128 block sums, single block
__global__ __launch_bounds__(128) void k_scan_bsums(int* bsum, int nb) {
  __shared__ int s[128];
  int t = threadIdx.x;
  s[t] = (t < nb) ? bsum[t] : 0;
  __syncthreads();
  for (int off = 1; off < 128; off <<= 1) {
    int v = (t >= off) ? s[t - off] : 0;
    __syncthreads();
    s[t] += v;
    __syncthreads();
  }
  if (t < nb) bsum[t] = (t == 0) ? 0 : s[t - 1];
}

// per-block exclusive scan (4 elems/thread) + block offset -> row_ptr & cursor copy
__global__ __launch_bounds__(256) void k_scan_final(const int* __restrict__ din, const int* __restrict__ bsum,
                                                    int* __restrict__ rp, int* __restrict__ cursor, int N, int E) {
  __shared__ int s[256];
  int t = threadIdx.x;
  int i0 = blockIdx.x * 1024 + t * 4;
  int v0 = 0, v1 = 0, v2 = 0, v3 = 0;
  if (i0 + 3 < N) {
    int4 q = *(const int4*)&din[i0];
    v0 = q.x; v1 = q.y; v2 = q.z; v3 = q.w;
  } else {
    if (i0 + 0 < N) v0 = din[i0 + 0];
    if (i0 + 1 < N) v1 = din[i0 + 1];
    if (i0 + 2 < N) v2 = din[i0 + 2];
    if (i0 + 3 < N) v3 = din[i0 + 3];
  }
  s[t] = v0 + v1 + v2 + v3;
  __syncthreads();
  for (int off = 1; off < 256; off <<= 1) {
    int v = (t >= off) ? s[t - off] : 0;
    __syncthreads();
    s[t] += v;
    __syncthreads();
  }
  int prev = ((t == 0) ? 0 : s[t - 1]) + bsum[blockIdx.x];
  int e0 = prev, e1 = e0 + v0, e2 = e1 + v1, e3 = e2 + v2;
  if (i0 + 3 < N) {
    *(int4*)&rp[i0] = make_int4(e0, e1, e2, e3);
    *(int4*)&cursor[i0] = make_int4(e0, e1, e2, e3);
  } else {
    if (i0 + 0 < N) { rp[i0 + 0] = e0; cursor[i0 + 0] = e0; }
    if (i0 + 1 < N) { rp[i0 + 1] = e1; cursor[i0 + 1] = e1; }
    if (i0 + 2 < N) { rp[i0 + 2] = e2; cursor[i0 + 2] = e2; }
    if (i0 + 3 < N) { rp[i0 + 3] = e3; cursor[i0 + 3] = e3; }
  }
  if (blockIdx.x == 0 && t == 0) rp[N] = E;
}

__global__ __launch_bounds__(256) void k_scatter(const int* __restrict__ src, const int* __restrict__ dst,
                                                 int* __restrict__ cursor, int* __restrict__ ci, int E) {
  int stride = gridDim.x * blockDim.x;
  for (int e = blockIdx.x * blockDim.x + threadIdx.x; e < E; e += stride) {
    int d = dst[e];
    int pos = atomicAdd(&cursor[d], 1);
    ci[pos] = src[e];
  }
}

// ---------------- Dense: out[r][c] = sum_k A[r][k]*scale[r]*W[k][c], K=128, 128 cols ----------------
// 64 rows/block, 256 threads, K chunked by 32. Thread: 4 rows x (4 + 4) cols.

__global__ __launch_bounds__(256) void k_gemm128(const float* __restrict__ A, const float* __restrict__ W,
                                                 const float* __restrict__ scale, float* __restrict__ out, int N) {
  __shared__ float As[64][36];   // +4 pad: rows 4 apart land 2-way (free), not 4-way
  __shared__ float Ws[32][128];
  int t = threadIdx.x;
  int row0 = blockIdx.x * 64;
  int colg = (t & 15) * 4;   // cols colg..+3 and colg+64..+67
  int rowg = (t >> 4) * 4;   // rows rowg..+3

  float acc[4][8];
#pragma unroll
  for (int r = 0; r < 4; r++)
#pragma unroll
    for (int c = 0; c < 8; c++) acc[r][c] = 0.f;

  for (int kb = 0; kb < 128; kb += 32) {
#pragma unroll
    for (int i = 0; i < 2; i++) {
      int f = t + i * 256;         // 0..511 float4 slots of 64x32 tile
      int r = f >> 3;
      int c4 = (f & 7) * 4;
      int g = row0 + r;
      float4 v = make_float4(0.f, 0.f, 0.f, 0.f);
      if (g < N) {
        v = *(const float4*)&A[(size_t)g * 128 + kb + c4];
        float sc = scale[g];
        v.x *= sc; v.y *= sc; v.z *= sc; v.w *= sc;
      }
      *(float4*)&As[r][c4] = v;
    }
#pragma unroll
    for (int i = 0; i < 4; i++) {
      int f = t + i * 256;         // 0..1023 float4 slots of 32x128 tile
      int kr = f >> 5;
      int c4 = (f & 31) * 4;
      *(float4*)&Ws[kr][c4] = *(const float4*)&W[(size_t)(kb + kr) * 128 + c4];
    }
    __syncthreads();
#pragma unroll
    for (int k = 0; k < 32; k++) {
      float4 w0 = *(const float4*)&Ws[k][colg];
      float4 w1 = *(const float4*)&Ws[k][colg + 64];
#pragma unroll
      for (int r = 0; r < 4; r++) {
        float a = As[rowg + r][k];
        acc[r][0] = fmaf(a, w0.x, acc[r][0]);
        acc[r][1] = fmaf(a, w0.y, acc[r][1]);
        acc[r][2] = fmaf(a, w0.z, acc[r][2]);
        acc[r][3] = fmaf(a, w0.w, acc[r][3]);
        acc[r][4] = fmaf(a, w1.x, acc[r][4]);
        acc[r][5] = fmaf(a, w1.y, acc[r][5]);
        acc[r][6] = fmaf(a, w1.z, acc[r][6]);
        acc[r][7] = fmaf(a, w1.w, acc[r][7]);
      }
    }
    __syncthreads();
  }
#pragma unroll
  for (int r = 0; r < 4; r++) {
    int g = row0 + rowg + r;
    if (g < N) {
      *(float4*)&out[(size_t)g * 128 + colg] = make_float4(acc[r][0], acc[r][1], acc[r][2], acc[r][3]);
      *(float4*)&out[(size_t)g * 128 + colg + 64] = make_float4(acc[r][4], acc[r][5], acc[r][6], acc[r][7]);
    }
  }
}

// ---------------- Sparse aggregation ----------------
// One wave per node. Half-wave (32 lanes) covers the full 128-feat row as float4/lane;
// the two halves walk different neighbors (p0+half, step 2), x2 unrolled -> 4 gathers in flight.
// Cross-half combine via __shfl_xor(...,32); lanes 0-31 write the row.

__global__ __launch_bounds__(256) void k_aggregate(const float* __restrict__ hin, const int* __restrict__ rp,
                                                   const int* __restrict__ ci, const float* __restrict__ c_dst,
                                                   const float* __restrict__ bias, float* __restrict__ hout, int N) {
  int v = blockIdx.x * 4 + (threadIdx.x >> 6);
  if (v >= N) return;
  int half = (threadIdx.x >> 5) & 1;
  int f4 = (threadIdx.x & 31) * 4;
  const float* hb = hin + f4;
  int pe = rp[v + 1];
  int p = rp[v] + half;
  float4 a0 = make_float4(0.f, 0.f, 0.f, 0.f);
  float4 a1 = make_float4(0.f, 0.f, 0.f, 0.f);
  for (; p + 2 < pe; p += 4) {
    int u0 = ci[p];
    int u1 = ci[p + 2];
    float4 t0 = *(const float4*)&hb[(size_t)u0 * 128];
    float4 t1 = *(const float4*)&hb[(size_t)u1 * 128];
    a0.x += t0.x; a0.y += t0.y; a0.z += t0.z; a0.w += t0.w;
    a1.x += t1.x; a1.y += t1.y; a1.z += t1.z; a1.w += t1.w;
  }
  for (; p < pe; p += 2) {
    int u = ci[p];
    float4 t = *(const float4*)&hb[(size_t)u * 128];
    a0.x += t.x; a0.y += t.y; a0.z += t.z; a0.w += t.w;
  }
  a0.x += a1.x; a0.y += a1.y; a0.z += a1.z; a0.w += a1.w;
  a0.x += __shfl_xor(a0.x, 32);
  a0.y += __shfl_xor(a0.y, 32);
  a0.z += __shfl_xor(a0.z, 32);
  a0.w += __shfl_xor(a0.w, 32);
  if (half == 0) {
    float cd = c_dst[v];
    float4 b = *(const float4*)&bias[f4];
    float4 o;
    o.x = fmaxf(fmaf(a0.x, cd, b.x), 0.f);
    o.y = fmaxf(fmaf(a0.y, cd, b.y), 0.f);
    o.z = fmaxf(fmaf(a0.z, cd, b.z), 0.f);
    o.w = fmaxf(fmaf(a0.w, cd, b.w), 0.f);
    *(float4*)&hout[(size_t)v * 128 + f4] = o;
  }
}

// ---------------- Classifier: out[N,47] = h @ Wc + bc ----------------

__global__ __launch_bounds__(256) void k_classifier(const float* __restrict__ h, const float* __restrict__ Wc,
                                                    const float* __restrict__ bc, float* __restrict__ out, int N) {
  __shared__ float hs[64][128];
  __shared__ float Wct[47][132];  // transposed, padded
  __shared__ float bs[47];
  int t = threadIdx.x;
  int row0 = blockIdx.x * 64;
  for (int f = t; f < 128 * 47; f += 256) {
    int k = f / 47;
    int c = f - k * 47;
    Wct[c][k] = Wc[f];
  }
  if (t < 47) bs[t] = bc[t];
#pragma unroll
  for (int i = 0; i < 8; i++) {
    int f = t + i * 256;           // 2048 float4 slots of 64x128
    int r = f >> 5;
    int c4 = (f & 31) * 4;
    int g = row0 + r;
    float4 v = make_float4(0.f, 0.f, 0.f, 0.f);
    if (g < N) v = *(const float4*)&h[(size_t)g * 128 + c4];
    *(float4*)&hs[r][c4] = v;
  }
  __syncthreads();
  for (int idx = t; idx < 64 * 47; idx += 256) {
    int r = idx / 47;
    int c = idx - r * 47;
    int g = row0 + r;
    float s = 0.f;
#pragma unroll
    for (int k4 = 0; k4 < 128; k4 += 4) {
      float4 a = *(const float4*)&hs[r][k4];
      float4 w = *(const float4*)&Wct[c][k4];
      s = fmaf(a.x, w.x, s);
      s = fmaf(a.y, w.y, s);
      s = fmaf(a.z, w.z, s);
      s = fmaf(a.w, w.w, s);
    }
    if (g < N) out[(size_t)g * 47 + c] = s + bs[c];
  }
}

// ---------------- launch ----------------

extern "C" void kernel_launch(void* const* d_in, const int* in_sizes, int n_in,
                              void* d_out, int out_size, void* d_ws, size_t ws_size,
                              hipStream_t stream) {
  const float* x  = (const float*)d_in[0];
  const int* edges = (const int*)d_in[1];
  const float* W0 = (const float*)d_in[2];
  const float* b0 = (const float*)d_in[3];
  const float* W1 = (const float*)d_in[4];
  const float* b1 = (const float*)d_in[5];
  const float* Wc = (const float*)d_in[6];
  const float* bc = (const float*)d_in[7];
  float* out = (float*)d_out;

  int N = in_sizes[0] / 128;
  int E = in_sizes[1] / 2;
  const int* src = edges;
  const int* dst = edges + E;

  char* base = (char*)d_ws;
  size_t off = 0;
  auto alloc = [&](size_t bytes) -> void* {
    void* p = base + off;
    off += (bytes + 255) & ~(size_t)255;
    return p;
  };
  float* c_src = (float*)alloc((size_t)N * 4);
  float* c_dst = (float*)alloc((size_t)N * 4);
  int* deg = (int*)alloc((size_t)2 * N * 4);   // [deg_out | deg_in]
  int* deg_out = deg;
  int* deg_in = deg + N;
  int* row_ptr = (int*)alloc((size_t)(N + 1) * 4);
  int* cursor = (int*)alloc((size_t)N * 4);
  int* bsum = (int*)alloc(1024 * 4);
  int* col_idx = (int*)alloc((size_t)E * 4);
  float* h0 = (float*)alloc((size_t)N * 128 * 4);
  float* h1 = (float*)alloc((size_t)N * 128 * 4);

  int nb = (N + 1023) / 1024;

  hipMemsetAsync(deg, 0, (size_t)2 * N * 4, stream);
  k_histo<<<1024, 256, 0, stream>>>(src, dst, E, deg_out, deg_in);
  k_coeffs<<<(N + 255) / 256, 256, 0, stream>>>(deg_out, deg_in, c_src, c_dst, N);
  k_scan_partial<<<nb, 256, 0, stream>>>(deg_in, bsum, N);
  k_scan_bsums<<<1, 128, 0, stream>>>(bsum, nb);
  k_scan_final<<<nb, 256, 0, stream>>>(deg_in, bsum, row_ptr, cursor, N, E);
  k_scatter<<<1024, 256, 0, stream>>>(src, dst, cursor, col_idx, E);

  k_gemm128<<<(N + 63) / 64, 256, 0, stream>>>(x, W0, c_src, h0, N);
  k_aggregate<<<(N + 3) / 4, 256, 0, stream>>>(h0, row_ptr, col_idx, c_dst, b0, h1, N);
  k_gemm128<<<(N + 63) / 64, 256, 0, stream>>>(h1, W1, c_src, h0, N);
  k_aggregate<<<(N + 3) / 4, 256, 0, stream>>>(h0, row_ptr, col_idx, c_dst, b1, h1, N);
  k_classifier<<<(N + 63) / 64, 256, 0, stream>>>(h1, Wc, bc, out, N);
}

// Round 3
// 597.976 us; speedup vs baseline: 1.4113x; 1.2561x over previous
//
#include <hip/hip_runtime.h>

// GCN: h0 = relu(c_dst ⊙ Agg(c_src ⊙ x @ W0) + b0); h1 = same with W1; out = h1 @ Wc + bc
// R2: CSR build via bucketed two-phase partition (no global counting-scatter).
//   Phase A: partition edges by dst>>8 into NB buckets (LDS histo -> scans -> LDS-cursor scatter
//            of packed (dstrel<<SRC_BITS)|src). Per-(block,bucket) chunks are contiguous.
//   Phase B: per bucket: LDS histo (-> c_dst, row_ptr via LDS scan), LDS-cursor scatter -> col_idx.

#define PB 256          // partition blocks
#define BSHIFT 8        // bucket = dst >> 8 (256 nodes/bucket)

// ---------------- out-degree histogram (for c_src) ----------------

__global__ __launch_bounds__(256) void k_histo(const int* __restrict__ src, int E, int* __restrict__ dout) {
  int stride = gridDim.x * blockDim.x;
  for (int e = blockIdx.x * blockDim.x + threadIdx.x; e < E; e += stride)
    atomicAdd(&dout[src[e]], 1);
}

__global__ __launch_bounds__(256) void k_coeffs_src(const int* __restrict__ dout, float* __restrict__ c_src, int N) {
  int i = blockIdx.x * blockDim.x + threadIdx.x;
  if (i < N) c_src[i] = rsqrtf((float)max(dout[i], 1));
}

// ---------------- Phase A: bucket counts ----------------

__global__ __launch_bounds__(256) void k_count(const int* __restrict__ dst, int E, int per_blk, int NB,
                                               int* __restrict__ cntT) {
  __shared__ int cnt[512];
  for (int i = threadIdx.x; i < NB; i += 256) cnt[i] = 0;
  __syncthreads();
  int e0 = blockIdx.x * per_blk, e1 = min(E, e0 + per_blk);
  for (int e = e0 + threadIdx.x; e < e1; e += 256) atomicAdd(&cnt[dst[e] >> BSHIFT], 1);
  __syncthreads();
  for (int i = threadIdx.x; i < NB; i += 256) cntT[i * PB + blockIdx.x] = cnt[i];
}

// exclusive scan of each bucket's 256 per-block counts -> per-block offsets + bucket totals
__global__ __launch_bounds__(256) void k_scanblk(const int* __restrict__ cntT, int* __restrict__ offsT,
                                                 int* __restrict__ total) {
  __shared__ int s[256];
  int b = blockIdx.x, t = threadIdx.x;
  int v = cntT[b * PB + t];
  s[t] = v;
  __syncthreads();
  for (int off = 1; off < 256; off <<= 1) {
    int x = (t >= off) ? s[t - off] : 0;
    __syncthreads();
    s[t] += x;
    __syncthreads();
  }
  offsT[b * PB + t] = s[t] - v;
  if (t == 255) total[b] = s[255];
}

// exclusive scan of bucket totals -> bucket bases; also row_ptr[N]=E
__global__ __launch_bounds__(512) void k_scantot(const int* __restrict__ total, int NB, int E,
                                                 int* __restrict__ bbase, int* __restrict__ row_ptr, int N) {
  __shared__ int s[512];
  int t = threadIdx.x;
  int v = (t < NB) ? total[t] : 0;
  s[t] = v;
  __syncthreads();
  for (int off = 1; off < 512; off <<= 1) {
    int x = (t >= off) ? s[t - off] : 0;
    __syncthreads();
    s[t] += x;
    __syncthreads();
  }
  if (t < NB) bbase[t] = s[t] - v;
  if (t == 0) { bbase[NB] = E; row_ptr[N] = E; }
}

// ---------------- Phase A: partition scatter ----------------

__global__ __launch_bounds__(256) void k_partition(const int* __restrict__ src, const int* __restrict__ dst,
                                                   int E, int per_blk, int NB,
                                                   const int* __restrict__ offsT, const int* __restrict__ bbase,
                                                   unsigned* __restrict__ ebuf, int src_bits) {
  __shared__ int cur[512];
  for (int i = threadIdx.x; i < NB; i += 256) cur[i] = bbase[i] + offsT[i * PB + blockIdx.x];
  __syncthreads();
  int e0 = blockIdx.x * per_blk, e1 = min(E, e0 + per_blk);
  for (int e = e0 + threadIdx.x; e < e1; e += 256) {
    int d = dst[e], s = src[e];
    int pos = atomicAdd(&cur[d >> BSHIFT], 1);
    ebuf[pos] = ((unsigned)(d & ((1 << BSHIFT) - 1)) << src_bits) | (unsigned)s;
  }
}

// ---------------- Phase B: per-bucket finalize -> row_ptr, c_dst, col_idx ----------------

__global__ __launch_bounds__(256) void k_finalize(const unsigned* __restrict__ ebuf, const int* __restrict__ bbase,
                                                  int N, int src_bits, int* __restrict__ row_ptr,
                                                  float* __restrict__ c_dst, int* __restrict__ col_idx) {
  __shared__ int cnt[256];
  __shared__ int s[256];
  __shared__ int cur[256];
  int b = blockIdx.x, t = threadIdx.x;
  int r0 = bbase[b], r1 = bbase[b + 1];
  cnt[t] = 0;
  __syncthreads();
  for (int i = r0 + t; i < r1; i += 256) atomicAdd(&cnt[ebuf[i] >> src_bits], 1);
  __syncthreads();
  int v = cnt[t];
  s[t] = v;
  __syncthreads();
  for (int off = 1; off < 256; off <<= 1) {
    int x = (t >= off) ? s[t - off] : 0;
    __syncthreads();
    s[t] += x;
    __syncthreads();
  }
  int ex = s[t] - v;
  cur[t] = ex;
  int node = (b << BSHIFT) + t;
  if (node < N) {
    row_ptr[node] = r0 + ex;
    c_dst[node] = rsqrtf((float)max(v, 1));
  }
  __syncthreads();
  unsigned smask = (1u << src_bits) - 1u;
  for (int i = r0 + t; i < r1; i += 256) {
    unsigned e = ebuf[i];
    int pos = r0 + atomicAdd(&cur[e >> src_bits], 1);
    col_idx[pos] = (int)(e & smask);
  }
}

// ---------------- Dense: out[r][c] = sum_k A[r][k]*scale[r]*W[k][c], K=128, 128 cols ----------------

__global__ __launch_bounds__(256) void k_gemm128(const float* __restrict__ A, const float* __restrict__ W,
                                                 const float* __restrict__ scale, float* __restrict__ out, int N) {
  __shared__ float As[64][36];
  __shared__ float Ws[32][128];
  int t = threadIdx.x;
  int row0 = blockIdx.x * 64;
  int colg = (t & 15) * 4;
  int rowg = (t >> 4) * 4;

  float acc[4][8];
#pragma unroll
  for (int r = 0; r < 4; r++)
#pragma unroll
    for (int c = 0; c < 8; c++) acc[r][c] = 0.f;

  for (int kb = 0; kb < 128; kb += 32) {
#pragma unroll
    for (int i = 0; i < 2; i++) {
      int f = t + i * 256;
      int r = f >> 3;
      int c4 = (f & 7) * 4;
      int g = row0 + r;
      float4 v = make_float4(0.f, 0.f, 0.f, 0.f);
      if (g < N) {
        v = *(const float4*)&A[(size_t)g * 128 + kb + c4];
        float sc = scale[g];
        v.x *= sc; v.y *= sc; v.z *= sc; v.w *= sc;
      }
      *(float4*)&As[r][c4] = v;
    }
#pragma unroll
    for (int i = 0; i < 4; i++) {
      int f = t + i * 256;
      int kr = f >> 5;
      int c4 = (f & 31) * 4;
      *(float4*)&Ws[kr][c4] = *(const float4*)&W[(size_t)(kb + kr) * 128 + c4];
    }
    __syncthreads();
#pragma unroll
    for (int k = 0; k < 32; k++) {
      float4 w0 = *(const float4*)&Ws[k][colg];
      float4 w1 = *(const float4*)&Ws[k][colg + 64];
#pragma unroll
      for (int r = 0; r < 4; r++) {
        float a = As[rowg + r][k];
        acc[r][0] = fmaf(a, w0.x, acc[r][0]);
        acc[r][1] = fmaf(a, w0.y, acc[r][1]);
        acc[r][2] = fmaf(a, w0.z, acc[r][2]);
        acc[r][3] = fmaf(a, w0.w, acc[r][3]);
        acc[r][4] = fmaf(a, w1.x, acc[r][4]);
        acc[r][5] = fmaf(a, w1.y, acc[r][5]);
        acc[r][6] = fmaf(a, w1.z, acc[r][6]);
        acc[r][7] = fmaf(a, w1.w, acc[r][7]);
      }
    }
    __syncthreads();
  }
#pragma unroll
  for (int r = 0; r < 4; r++) {
    int g = row0 + rowg + r;
    if (g < N) {
      *(float4*)&out[(size_t)g * 128 + colg] = make_float4(acc[r][0], acc[r][1], acc[r][2], acc[r][3]);
      *(float4*)&out[(size_t)g * 128 + colg + 64] = make_float4(acc[r][4], acc[r][5], acc[r][6], acc[r][7]);
    }
  }
}

// ---------------- Sparse aggregation (R1 version) ----------------

__global__ __launch_bounds__(256) void k_aggregate(const float* __restrict__ hin, const int* __restrict__ rp,
                                                   const int* __restrict__ ci, const float* __restrict__ c_dst,
                                                   const float* __restrict__ bias, float* __restrict__ hout, int N) {
  int v = blockIdx.x * 4 + (threadIdx.x >> 6);
  if (v >= N) return;
  int half = (threadIdx.x >> 5) & 1;
  int f4 = (threadIdx.x & 31) * 4;
  const float* hb = hin + f4;
  int pe = rp[v + 1];
  int p = rp[v] + half;
  float4 a0 = make_float4(0.f, 0.f, 0.f, 0.f);
  float4 a1 = make_float4(0.f, 0.f, 0.f, 0.f);
  for (; p + 2 < pe; p += 4) {
    int u0 = ci[p];
    int u1 = ci[p + 2];
    float4 t0 = *(const float4*)&hb[(size_t)u0 * 128];
    float4 t1 = *(const float4*)&hb[(size_t)u1 * 128];
    a0.x += t0.x; a0.y += t0.y; a0.z += t0.z; a0.w += t0.w;
    a1.x += t1.x; a1.y += t1.y; a1.z += t1.z; a1.w += t1.w;
  }
  for (; p < pe; p += 2) {
    int u = ci[p];
    float4 t = *(const float4*)&hb[(size_t)u * 128];
    a0.x += t.x; a0.y += t.y; a0.z += t.z; a0.w += t.w;
  }
  a0.x += a1.x; a0.y += a1.y; a0.z += a1.z; a0.w += a1.w;
  a0.x += __shfl_xor(a0.x, 32);
  a0.y += __shfl_xor(a0.y, 32);
  a0.z += __shfl_xor(a0.z, 32);
  a0.w += __shfl_xor(a0.w, 32);
  if (half == 0) {
    float cd = c_dst[v];
    float4 b = *(const float4*)&bias[f4];
    float4 o;
    o.x = fmaxf(fmaf(a0.x, cd, b.x), 0.f);
    o.y = fmaxf(fmaf(a0.y, cd, b.y), 0.f);
    o.z = fmaxf(fmaf(a0.z, cd, b.z), 0.f);
    o.w = fmaxf(fmaf(a0.w, cd, b.w), 0.f);
    *(float4*)&hout[(size_t)v * 128 + f4] = o;
  }
}

// ---------------- Classifier: out[N,47] = h @ Wc + bc ----------------

__global__ __launch_bounds__(256) void k_classifier(const float* __restrict__ h, const float* __restrict__ Wc,
                                                    const float* __restrict__ bc, float* __restrict__ out, int N) {
  __shared__ float hs[64][128];
  __shared__ float Wct[47][132];
  __shared__ float bs[47];
  int t = threadIdx.x;
  int row0 = blockIdx.x * 64;
  for (int f = t; f < 128 * 47; f += 256) {
    int k = f / 47;
    int c = f - k * 47;
    Wct[c][k] = Wc[f];
  }
  if (t < 47) bs[t] = bc[t];
#pragma unroll
  for (int i = 0; i < 8; i++) {
    int f = t + i * 256;
    int r = f >> 5;
    int c4 = (f & 31) * 4;
    int g = row0 + r;
    float4 v = make_float4(0.f, 0.f, 0.f, 0.f);
    if (g < N) v = *(const float4*)&h[(size_t)g * 128 + c4];
    *(float4*)&hs[r][c4] = v;
  }
  __syncthreads();
  for (int idx = t; idx < 64 * 47; idx += 256) {
    int r = idx / 47;
    int c = idx - r * 47;
    int g = row0 + r;
    float s = 0.f;
#pragma unroll
    for (int k4 = 0; k4 < 128; k4 += 4) {
      float4 a = *(const float4*)&hs[r][k4];
      float4 w = *(const float4*)&Wct[c][k4];
      s = fmaf(a.x, w.x, s);
      s = fmaf(a.y, w.y, s);
      s = fmaf(a.z, w.z, s);
      s = fmaf(a.w, w.w, s);
    }
    if (g < N) out[(size_t)g * 47 + c] = s + bs[c];
  }
}

// ---------------- launch ----------------

extern "C" void kernel_launch(void* const* d_in, const int* in_sizes, int n_in,
                              void* d_out, int out_size, void* d_ws, size_t ws_size,
                              hipStream_t stream) {
  const float* x  = (const float*)d_in[0];
  const int* edges = (const int*)d_in[1];
  const float* W0 = (const float*)d_in[2];
  const float* b0 = (const float*)d_in[3];
  const float* W1 = (const float*)d_in[4];
  const float* b1 = (const float*)d_in[5];
  const float* Wc = (const float*)d_in[6];
  const float* bc = (const float*)d_in[7];
  float* out = (float*)d_out;

  int N = in_sizes[0] / 128;
  int E = in_sizes[1] / 2;
  const int* src = edges;
  const int* dst = edges + E;

  int NB = (N + ((1 << BSHIFT) - 1)) >> BSHIFT;   // 391 for N=100000 (<=512 required)
  int src_bits = 0;
  while ((1 << src_bits) < N) src_bits++;          // 17 for N=100000
  int per_blk = (E + PB - 1) / PB;

  char* base = (char*)d_ws;
  size_t off = 0;
  auto alloc = [&](size_t bytes) -> void* {
    void* p = base + off;
    off += (bytes + 255) & ~(size_t)255;
    return p;
  };
  float* c_src = (float*)alloc((size_t)N * 4);
  float* c_dst = (float*)alloc((size_t)N * 4);
  int* deg_out = (int*)alloc((size_t)N * 4);
  int* row_ptr = (int*)alloc((size_t)(N + 1) * 4);
  int* col_idx = (int*)alloc((size_t)E * 4);
  float* h0 = (float*)alloc((size_t)N * 128 * 4);
  float* h1 = (float*)alloc((size_t)N * 128 * 4);

  // build-time scratch carved out of h1 (dead until first k_aggregate writes h1)
  char* hb = (char*)h1;
  unsigned* ebuf = (unsigned*)hb;            hb += (size_t)E * 4;
  int* cntT = (int*)hb;                      hb += (size_t)NB * PB * 4;
  int* offsT = (int*)hb;                     hb += (size_t)NB * PB * 4;
  int* total = (int*)hb;                     hb += (size_t)NB * 4;
  int* bbase = (int*)hb;                     hb += (size_t)(NB + 1) * 4;

  hipMemsetAsync(deg_out, 0, (size_t)N * 4, stream);
  k_histo<<<1024, 256, 0, stream>>>(src, E, deg_out);
  k_coeffs_src<<<(N + 255) / 256, 256, 0, stream>>>(deg_out, c_src, N);

  k_count<<<PB, 256, 0, stream>>>(dst, E, per_blk, NB, cntT);
  k_scanblk<<<NB, 256, 0, stream>>>(cntT, offsT, total);
  k_scantot<<<1, 512, 0, stream>>>(total, NB, E, bbase, row_ptr, N);
  k_partition<<<PB, 256, 0, stream>>>(src, dst, E, per_blk, NB, offsT, bbase, ebuf, src_bits);
  k_finalize<<<NB, 256, 0, stream>>>(ebuf, bbase, N, src_bits, row_ptr, c_dst, col_idx);

  k_gemm128<<<(N + 63) / 64, 256, 0, stream>>>(x, W0, c_src, h0, N);
  k_aggregate<<<(N + 3) / 4, 256, 0, stream>>>(h0, row_ptr, col_idx, c_dst, b0, h1, N);
  k_gemm128<<<(N + 63) / 64, 256, 0, stream>>>(h1, W1, c_src, h0, N);
  k_aggregate<<<(N + 3) / 4, 256, 0, stream>>>(h0, row_ptr, col_idx, c_dst, b1, h1, N);
  k_classifier<<<(N + 63) / 64, 256, 0, stream>>>(h1, Wc, bc, out, N);
}

// Round 4
// 506.967 us; speedup vs baseline: 1.6647x; 1.1795x over previous
//
#include <hip/hip_runtime.h>
#include <hip/hip_fp16.h>

// GCN: h0 = relu(c_dst ⊙ Agg(c_src ⊙ x @ W0) + b0); h1 = same with W1; out = h1 @ Wc + bc
// R3: GEMM outputs stored fp16 (h = 25.6 MB <= 32 MB aggregate L2) -> aggregate gathers
//     half the bytes and mostly L2-hit. Aggregate unrolled to 8 edges/wave.
//     Aggregate outputs stay fp32 (only two fp16 roundings on the whole path).

#define PB 256          // partition blocks
#define BSHIFT 8        // bucket = dst >> 8 (256 nodes/bucket)

// ---------------- out-degree histogram (for c_src) ----------------

__global__ __launch_bounds__(256) void k_histo(const int* __restrict__ src, int E, int* __restrict__ dout) {
  int stride = gridDim.x * blockDim.x;
  for (int e = blockIdx.x * blockDim.x + threadIdx.x; e < E; e += stride)
    atomicAdd(&dout[src[e]], 1);
}

__global__ __launch_bounds__(256) void k_coeffs_src(const int* __restrict__ dout, float* __restrict__ c_src, int N) {
  int i = blockIdx.x * blockDim.x + threadIdx.x;
  if (i < N) c_src[i] = rsqrtf((float)max(dout[i], 1));
}

// ---------------- Phase A: bucket counts ----------------

__global__ __launch_bounds__(256) void k_count(const int* __restrict__ dst, int E, int per_blk, int NB,
                                               int* __restrict__ cntT) {
  __shared__ int cnt[512];
  for (int i = threadIdx.x; i < NB; i += 256) cnt[i] = 0;
  __syncthreads();
  int e0 = blockIdx.x * per_blk, e1 = min(E, e0 + per_blk);
  for (int e = e0 + threadIdx.x; e < e1; e += 256) atomicAdd(&cnt[dst[e] >> BSHIFT], 1);
  __syncthreads();
  for (int i = threadIdx.x; i < NB; i += 256) cntT[i * PB + blockIdx.x] = cnt[i];
}

__global__ __launch_bounds__(256) void k_scanblk(const int* __restrict__ cntT, int* __restrict__ offsT,
                                                 int* __restrict__ total) {
  __shared__ int s[256];
  int b = blockIdx.x, t = threadIdx.x;
  int v = cntT[b * PB + t];
  s[t] = v;
  __syncthreads();
  for (int off = 1; off < 256; off <<= 1) {
    int x = (t >= off) ? s[t - off] : 0;
    __syncthreads();
    s[t] += x;
    __syncthreads();
  }
  offsT[b * PB + t] = s[t] - v;
  if (t == 255) total[b] = s[255];
}

__global__ __launch_bounds__(512) void k_scantot(const int* __restrict__ total, int NB, int E,
                                                 int* __restrict__ bbase, int* __restrict__ row_ptr, int N) {
  __shared__ int s[512];
  int t = threadIdx.x;
  int v = (t < NB) ? total[t] : 0;
  s[t] = v;
  __syncthreads();
  for (int off = 1; off < 512; off <<= 1) {
    int x = (t >= off) ? s[t - off] : 0;
    __syncthreads();
    s[t] += x;
    __syncthreads();
  }
  if (t < NB) bbase[t] = s[t] - v;
  if (t == 0) { bbase[NB] = E; row_ptr[N] = E; }
}

// ---------------- Phase A: partition scatter ----------------

__global__ __launch_bounds__(256) void k_partition(const int* __restrict__ src, const int* __restrict__ dst,
                                                   int E, int per_blk, int NB,
                                                   const int* __restrict__ offsT, const int* __restrict__ bbase,
                                                   unsigned* __restrict__ ebuf, int src_bits) {
  __shared__ int cur[512];
  for (int i = threadIdx.x; i < NB; i += 256) cur[i] = bbase[i] + offsT[i * PB + blockIdx.x];
  __syncthreads();
  int e0 = blockIdx.x * per_blk, e1 = min(E, e0 + per_blk);
  for (int e = e0 + threadIdx.x; e < e1; e += 256) {
    int d = dst[e], s = src[e];
    int pos = atomicAdd(&cur[d >> BSHIFT], 1);
    ebuf[pos] = ((unsigned)(d & ((1 << BSHIFT) - 1)) << src_bits) | (unsigned)s;
  }
}

// ---------------- Phase B: per-bucket finalize -> row_ptr, c_dst, col_idx ----------------

__global__ __launch_bounds__(256) void k_finalize(const unsigned* __restrict__ ebuf, const int* __restrict__ bbase,
                                                  int N, int src_bits, int* __restrict__ row_ptr,
                                                  float* __restrict__ c_dst, int* __restrict__ col_idx) {
  __shared__ int cnt[256];
  __shared__ int s[256];
  __shared__ int cur[256];
  int b = blockIdx.x, t = threadIdx.x;
  int r0 = bbase[b], r1 = bbase[b + 1];
  cnt[t] = 0;
  __syncthreads();
  for (int i = r0 + t; i < r1; i += 256) atomicAdd(&cnt[ebuf[i] >> src_bits], 1);
  __syncthreads();
  int v = cnt[t];
  s[t] = v;
  __syncthreads();
  for (int off = 1; off < 256; off <<= 1) {
    int x = (t >= off) ? s[t - off] : 0;
    __syncthreads();
    s[t] += x;
    __syncthreads();
  }
  int ex = s[t] - v;
  cur[t] = ex;
  int node = (b << BSHIFT) + t;
  if (node < N) {
    row_ptr[node] = r0 + ex;
    c_dst[node] = rsqrtf((float)max(v, 1));
  }
  __syncthreads();
  unsigned smask = (1u << src_bits) - 1u;
  for (int i = r0 + t; i < r1; i += 256) {
    unsigned e = ebuf[i];
    int pos = r0 + atomicAdd(&cur[e >> src_bits], 1);
    col_idx[pos] = (int)(e & smask);
  }
}

// ---------------- Dense: out[r][c] = sum_k A[r][k]*scale[r]*W[k][c], fp32 in, fp16 out ----------------

__global__ __launch_bounds__(256) void k_gemm128_h(const float* __restrict__ A, const float* __restrict__ W,
                                                   const float* __restrict__ scale, __half* __restrict__ out, int N) {
  __shared__ float As[64][36];
  __shared__ float Ws[32][128];
  int t = threadIdx.x;
  int row0 = blockIdx.x * 64;
  int colg = (t & 15) * 4;
  int rowg = (t >> 4) * 4;

  float acc[4][8];
#pragma unroll
  for (int r = 0; r < 4; r++)
#pragma unroll
    for (int c = 0; c < 8; c++) acc[r][c] = 0.f;

  for (int kb = 0; kb < 128; kb += 32) {
#pragma unroll
    for (int i = 0; i < 2; i++) {
      int f = t + i * 256;
      int r = f >> 3;
      int c4 = (f & 7) * 4;
      int g = row0 + r;
      float4 v = make_float4(0.f, 0.f, 0.f, 0.f);
      if (g < N) {
        v = *(const float4*)&A[(size_t)g * 128 + kb + c4];
        float sc = scale[g];
        v.x *= sc; v.y *= sc; v.z *= sc; v.w *= sc;
      }
      *(float4*)&As[r][c4] = v;
    }
#pragma unroll
    for (int i = 0; i < 4; i++) {
      int f = t + i * 256;
      int kr = f >> 5;
      int c4 = (f & 31) * 4;
      *(float4*)&Ws[kr][c4] = *(const float4*)&W[(size_t)(kb + kr) * 128 + c4];
    }
    __syncthreads();
#pragma unroll
    for (int k = 0; k < 32; k++) {
      float4 w0 = *(const float4*)&Ws[k][colg];
      float4 w1 = *(const float4*)&Ws[k][colg + 64];
#pragma unroll
      for (int r = 0; r < 4; r++) {
        float a = As[rowg + r][k];
        acc[r][0] = fmaf(a, w0.x, acc[r][0]);
        acc[r][1] = fmaf(a, w0.y, acc[r][1]);
        acc[r][2] = fmaf(a, w0.z, acc[r][2]);
        acc[r][3] = fmaf(a, w0.w, acc[r][3]);
        acc[r][4] = fmaf(a, w1.x, acc[r][4]);
        acc[r][5] = fmaf(a, w1.y, acc[r][5]);
        acc[r][6] = fmaf(a, w1.z, acc[r][6]);
        acc[r][7] = fmaf(a, w1.w, acc[r][7]);
      }
    }
    __syncthreads();
  }
#pragma unroll
  for (int r = 0; r < 4; r++) {
    int g = row0 + rowg + r;
    if (g < N) {
      __half2 p0 = __float22half2_rn(make_float2(acc[r][0], acc[r][1]));
      __half2 p1 = __float22half2_rn(make_float2(acc[r][2], acc[r][3]));
      __half2 p2 = __float22half2_rn(make_float2(acc[r][4], acc[r][5]));
      __half2 p3 = __float22half2_rn(make_float2(acc[r][6], acc[r][7]));
      uint2 q0, q1;
      q0.x = *(unsigned*)&p0; q0.y = *(unsigned*)&p1;
      q1.x = *(unsigned*)&p2; q1.y = *(unsigned*)&p3;
      *(uint2*)&out[(size_t)g * 128 + colg] = q0;
      *(uint2*)&out[(size_t)g * 128 + colg + 64] = q1;
    }
  }
}

// ---------------- Sparse aggregation: fp16 rows in, fp32 out ----------------
// One wave per node; halves take edge parity; lane covers 4 feats (8 B). 8 edges/iter in flight.

__device__ __forceinline__ void acc_q(float4& a, uint2 q) {
  float2 f0 = __half22float2(*(__half2*)&q.x);
  float2 f1 = __half22float2(*(__half2*)&q.y);
  a.x += f0.x; a.y += f0.y; a.z += f1.x; a.w += f1.y;
}

__global__ __launch_bounds__(256) void k_aggregate_h(const __half* __restrict__ hin, const int* __restrict__ rp,
                                                     const int* __restrict__ ci, const float* __restrict__ c_dst,
                                                     const float* __restrict__ bias, float* __restrict__ hout, int N) {
  int v = blockIdx.x * 4 + (threadIdx.x >> 6);
  if (v >= N) return;
  int half_id = (threadIdx.x >> 5) & 1;
  int f4 = (threadIdx.x & 31) * 4;
  const __half* hb = hin + f4;
  int pe = rp[v + 1];
  int p = rp[v] + half_id;
  float4 a0 = make_float4(0.f, 0.f, 0.f, 0.f);
  float4 a1 = make_float4(0.f, 0.f, 0.f, 0.f);
  float4 a2 = make_float4(0.f, 0.f, 0.f, 0.f);
  float4 a3 = make_float4(0.f, 0.f, 0.f, 0.f);
  for (; p + 6 < pe; p += 8) {
    int u0 = ci[p];
    int u1 = ci[p + 2];
    int u2 = ci[p + 4];
    int u3 = ci[p + 6];
    uint2 q0 = *(const uint2*)(hb + (size_t)u0 * 128);
    uint2 q1 = *(const uint2*)(hb + (size_t)u1 * 128);
    uint2 q2 = *(const uint2*)(hb + (size_t)u2 * 128);
    uint2 q3 = *(const uint2*)(hb + (size_t)u3 * 128);
    acc_q(a0, q0);
    acc_q(a1, q1);
    acc_q(a2, q2);
    acc_q(a3, q3);
  }
  for (; p < pe; p += 2) {
    uint2 q = *(const uint2*)(hb + (size_t)ci[p] * 128);
    acc_q(a0, q);
  }
  a0.x += a1.x; a0.y += a1.y; a0.z += a1.z; a0.w += a1.w;
  a2.x += a3.x; a2.y += a3.y; a2.z += a3.z; a2.w += a3.w;
  a0.x += a2.x; a0.y += a2.y; a0.z += a2.z; a0.w += a2.w;
  a0.x += __shfl_xor(a0.x, 32);
  a0.y += __shfl_xor(a0.y, 32);
  a0.z += __shfl_xor(a0.z, 32);
  a0.w += __shfl_xor(a0.w, 32);
  if (half_id == 0) {
    float cd = c_dst[v];
    float4 b = *(const float4*)&bias[f4];
    float4 o;
    o.x = fmaxf(fmaf(a0.x, cd, b.x), 0.f);
    o.y = fmaxf(fmaf(a0.y, cd, b.y), 0.f);
    o.z = fmaxf(fmaf(a0.z, cd, b.z), 0.f);
    o.w = fmaxf(fmaf(a0.w, cd, b.w), 0.f);
    *(float4*)&hout[(size_t)v * 128 + f4] = o;
  }
}

// ---------------- Classifier: out[N,47] = h @ Wc + bc (fp32 in) ----------------

__global__ __launch_bounds__(256) void k_classifier(const float* __restrict__ h, const float* __restrict__ Wc,
                                                    const float* __restrict__ bc, float* __restrict__ out, int N) {
  __shared__ float hs[64][128];
  __shared__ float Wct[47][132];
  __shared__ float bs[47];
  int t = threadIdx.x;
  int row0 = blockIdx.x * 64;
  for (int f = t; f < 128 * 47; f += 256) {
    int k = f / 47;
    int c = f - k * 47;
    Wct[c][k] = Wc[f];
  }
  if (t < 47) bs[t] = bc[t];
#pragma unroll
  for (int i = 0; i < 8; i++) {
    int f = t + i * 256;
    int r = f >> 5;
    int c4 = (f & 31) * 4;
    int g = row0 + r;
    float4 v = make_float4(0.f, 0.f, 0.f, 0.f);
    if (g < N) v = *(const float4*)&h[(size_t)g * 128 + c4];
    *(float4*)&hs[r][c4] = v;
  }
  __syncthreads();
  for (int idx = t; idx < 64 * 47; idx += 256) {
    int r = idx / 47;
    int c = idx - r * 47;
    int g = row0 + r;
    float s = 0.f;
#pragma unroll
    for (int k4 = 0; k4 < 128; k4 += 4) {
      float4 a = *(const float4*)&hs[r][k4];
      float4 w = *(const float4*)&Wct[c][k4];
      s = fmaf(a.x, w.x, s);
      s = fmaf(a.y, w.y, s);
      s = fmaf(a.z, w.z, s);
      s = fmaf(a.w, w.w, s);
    }
    if (g < N) out[(size_t)g * 47 + c] = s + bs[c];
  }
}

// ---------------- launch ----------------

extern "C" void kernel_launch(void* const* d_in, const int* in_sizes, int n_in,
                              void* d_out, int out_size, void* d_ws, size_t ws_size,
                              hipStream_t stream) {
  const float* x  = (const float*)d_in[0];
  const int* edges = (const int*)d_in[1];
  const float* W0 = (const float*)d_in[2];
  const float* b0 = (const float*)d_in[3];
  const float* W1 = (const float*)d_in[4];
  const float* b1 = (const float*)d_in[5];
  const float* Wc = (const float*)d_in[6];
  const float* bc = (const float*)d_in[7];
  float* out = (float*)d_out;

  int N = in_sizes[0] / 128;
  int E = in_sizes[1] / 2;
  const int* src = edges;
  const int* dst = edges + E;

  int NB = (N + ((1 << BSHIFT) - 1)) >> BSHIFT;   // 391 for N=100000 (<=512 required)
  int src_bits = 0;
  while ((1 << src_bits) < N) src_bits++;          // 17 for N=100000
  int per_blk = (E + PB - 1) / PB;

  char* base = (char*)d_ws;
  size_t off = 0;
  auto alloc = [&](size_t bytes) -> void* {
    void* p = base + off;
    off += (bytes + 255) & ~(size_t)255;
    return p;
  };
  float* c_src = (float*)alloc((size_t)N * 4);
  float* c_dst = (float*)alloc((size_t)N * 4);
  int* deg_out = (int*)alloc((size_t)N * 4);
  int* row_ptr = (int*)alloc((size_t)(N + 1) * 4);
  int* col_idx = (int*)alloc((size_t)E * 4);
  __half* h0h = (__half*)alloc((size_t)N * 128 * 2);   // GEMM outputs (fp16, 25.6 MB)
  float* h1 = (float*)alloc((size_t)N * 128 * 4);      // aggregate outputs (fp32)

  // build-time scratch carved out of h1 (dead until first k_aggregate writes h1)
  char* hb = (char*)h1;
  unsigned* ebuf = (unsigned*)hb;            hb += (size_t)E * 4;
  int* cntT = (int*)hb;                      hb += (size_t)NB * PB * 4;
  int* offsT = (int*)hb;                     hb += (size_t)NB * PB * 4;
  int* total = (int*)hb;                     hb += (size_t)NB * 4;
  int* bbase = (int*)hb;                     hb += (size_t)(NB + 1) * 4;

  hipMemsetAsync(deg_out, 0, (size_t)N * 4, stream);
  k_histo<<<1024, 256, 0, stream>>>(src, E, deg_out);
  k_coeffs_src<<<(N + 255) / 256, 256, 0, stream>>>(deg_out, c_src, N);

  k_count<<<PB, 256, 0, stream>>>(dst, E, per_blk, NB, cntT);
  k_scanblk<<<NB, 256, 0, stream>>>(cntT, offsT, total);
  k_scantot<<<1, 512, 0, stream>>>(total, NB, E, bbase, row_ptr, N);
  k_partition<<<PB, 256, 0, stream>>>(src, dst, E, per_blk, NB, offsT, bbase, ebuf, src_bits);
  k_finalize<<<NB, 256, 0, stream>>>(ebuf, bbase, N, src_bits, row_ptr, c_dst, col_idx);

  k_gemm128_h<<<(N + 63) / 64, 256, 0, stream>>>(x, W0, c_src, h0h, N);
  k_aggregate_h<<<(N + 3) / 4, 256, 0, stream>>>(h0h, row_ptr, col_idx, c_dst, b0, h1, N);
  k_gemm128_h<<<(N + 63) / 64, 256, 0, stream>>>(h1, W1, c_src, h0h, N);
  k_aggregate_h<<<(N + 3) / 4, 256, 0, stream>>>(h0h, row_ptr, col_idx, c_dst, b1, h1, N);
  k_classifier<<<(N + 63) / 64, 256, 0, stream>>>(h1, Wc, bc, out, N);
}

// Round 5
// 474.115 us; speedup vs baseline: 1.7800x; 1.0693x over previous
//
#include <hip/hip_runtime.h>
#include <hip/hip_fp16.h>

// GCN: h0 = relu(c_dst ⊙ Agg(c_src ⊙ x @ W0) + b0); h1 = same with W1; out = h1 @ Wc + bc
// R4: classifier rewritten as register-tiled GEMM (256 rows x 48 cols per block,
//     4x12 micro-tile per thread, conflict-free LDS strides 33 / 48). Old version was
//     LDS-issue-bound with 6-way bank conflicts (1.17e7 conflicts, 57.8 KB LDS, 2 blocks/CU).

#define PB 256          // partition blocks
#define BSHIFT 8        // bucket = dst >> 8 (256 nodes/bucket)

// ---------------- out-degree histogram (for c_src) ----------------

__global__ __launch_bounds__(256) void k_histo(const int* __restrict__ src, int E, int* __restrict__ dout) {
  int stride = gridDim.x * blockDim.x;
  for (int e = blockIdx.x * blockDim.x + threadIdx.x; e < E; e += stride)
    atomicAdd(&dout[src[e]], 1);
}

__global__ __launch_bounds__(256) void k_coeffs_src(const int* __restrict__ dout, float* __restrict__ c_src, int N) {
  int i = blockIdx.x * blockDim.x + threadIdx.x;
  if (i < N) c_src[i] = rsqrtf((float)max(dout[i], 1));
}

// ---------------- Phase A: bucket counts ----------------

__global__ __launch_bounds__(256) void k_count(const int* __restrict__ dst, int E, int per_blk, int NB,
                                               int* __restrict__ cntT) {
  __shared__ int cnt[512];
  for (int i = threadIdx.x; i < NB; i += 256) cnt[i] = 0;
  __syncthreads();
  int e0 = blockIdx.x * per_blk, e1 = min(E, e0 + per_blk);
  for (int e = e0 + threadIdx.x; e < e1; e += 256) atomicAdd(&cnt[dst[e] >> BSHIFT], 1);
  __syncthreads();
  for (int i = threadIdx.x; i < NB; i += 256) cntT[i * PB + blockIdx.x] = cnt[i];
}

__global__ __launch_bounds__(256) void k_scanblk(const int* __restrict__ cntT, int* __restrict__ offsT,
                                                 int* __restrict__ total) {
  __shared__ int s[256];
  int b = blockIdx.x, t = threadIdx.x;
  int v = cntT[b * PB + t];
  s[t] = v;
  __syncthreads();
  for (int off = 1; off < 256; off <<= 1) {
    int x = (t >= off) ? s[t - off] : 0;
    __syncthreads();
    s[t] += x;
    __syncthreads();
  }
  offsT[b * PB + t] = s[t] - v;
  if (t == 255) total[b] = s[255];
}

__global__ __launch_bounds__(512) void k_scantot(const int* __restrict__ total, int NB, int E,
                                                 int* __restrict__ bbase, int* __restrict__ row_ptr, int N) {
  __shared__ int s[512];
  int t = threadIdx.x;
  int v = (t < NB) ? total[t] : 0;
  s[t] = v;
  __syncthreads();
  for (int off = 1; off < 512; off <<= 1) {
    int x = (t >= off) ? s[t - off] : 0;
    __syncthreads();
    s[t] += x;
    __syncthreads();
  }
  if (t < NB) bbase[t] = s[t] - v;
  if (t == 0) { bbase[NB] = E; row_ptr[N] = E; }
}

// ---------------- Phase A: partition scatter ----------------

__global__ __launch_bounds__(256) void k_partition(const int* __restrict__ src, const int* __restrict__ dst,
                                                   int E, int per_blk, int NB,
                                                   const int* __restrict__ offsT, const int* __restrict__ bbase,
                                                   unsigned* __restrict__ ebuf, int src_bits) {
  __shared__ int cur[512];
  for (int i = threadIdx.x; i < NB; i += 256) cur[i] = bbase[i] + offsT[i * PB + blockIdx.x];
  __syncthreads();
  int e0 = blockIdx.x * per_blk, e1 = min(E, e0 + per_blk);
  for (int e = e0 + threadIdx.x; e < e1; e += 256) {
    int d = dst[e], s = src[e];
    int pos = atomicAdd(&cur[d >> BSHIFT], 1);
    ebuf[pos] = ((unsigned)(d & ((1 << BSHIFT) - 1)) << src_bits) | (unsigned)s;
  }
}

// ---------------- Phase B: per-bucket finalize -> row_ptr, c_dst, col_idx ----------------

__global__ __launch_bounds__(256) void k_finalize(const unsigned* __restrict__ ebuf, const int* __restrict__ bbase,
                                                  int N, int src_bits, int* __restrict__ row_ptr,
                                                  float* __restrict__ c_dst, int* __restrict__ col_idx) {
  __shared__ int cnt[256];
  __shared__ int s[256];
  __shared__ int cur[256];
  int b = blockIdx.x, t = threadIdx.x;
  int r0 = bbase[b], r1 = bbase[b + 1];
  cnt[t] = 0;
  __syncthreads();
  for (int i = r0 + t; i < r1; i += 256) atomicAdd(&cnt[ebuf[i] >> src_bits], 1);
  __syncthreads();
  int v = cnt[t];
  s[t] = v;
  __syncthreads();
  for (int off = 1; off < 256; off <<= 1) {
    int x = (t >= off) ? s[t - off] : 0;
    __syncthreads();
    s[t] += x;
    __syncthreads();
  }
  int ex = s[t] - v;
  cur[t] = ex;
  int node = (b << BSHIFT) + t;
  if (node < N) {
    row_ptr[node] = r0 + ex;
    c_dst[node] = rsqrtf((float)max(v, 1));
  }
  __syncthreads();
  unsigned smask = (1u << src_bits) - 1u;
  for (int i = r0 + t; i < r1; i += 256) {
    unsigned e = ebuf[i];
    int pos = r0 + atomicAdd(&cur[e >> src_bits], 1);
    col_idx[pos] = (int)(e & smask);
  }
}

// ---------------- Dense: out[r][c] = sum_k A[r][k]*scale[r]*W[k][c], fp32 in, fp16 out ----------------

__global__ __launch_bounds__(256) void k_gemm128_h(const float* __restrict__ A, const float* __restrict__ W,
                                                   const float* __restrict__ scale, __half* __restrict__ out, int N) {
  __shared__ float As[64][36];
  __shared__ float Ws[32][128];
  int t = threadIdx.x;
  int row0 = blockIdx.x * 64;
  int colg = (t & 15) * 4;
  int rowg = (t >> 4) * 4;

  float acc[4][8];
#pragma unroll
  for (int r = 0; r < 4; r++)
#pragma unroll
    for (int c = 0; c < 8; c++) acc[r][c] = 0.f;

  for (int kb = 0; kb < 128; kb += 32) {
#pragma unroll
    for (int i = 0; i < 2; i++) {
      int f = t + i * 256;
      int r = f >> 3;
      int c4 = (f & 7) * 4;
      int g = row0 + r;
      float4 v = make_float4(0.f, 0.f, 0.f, 0.f);
      if (g < N) {
        v = *(const float4*)&A[(size_t)g * 128 + kb + c4];
        float sc = scale[g];
        v.x *= sc; v.y *= sc; v.z *= sc; v.w *= sc;
      }
      *(float4*)&As[r][c4] = v;
    }
#pragma unroll
    for (int i = 0; i < 4; i++) {
      int f = t + i * 256;
      int kr = f >> 5;
      int c4 = (f & 31) * 4;
      *(float4*)&Ws[kr][c4] = *(const float4*)&W[(size_t)(kb + kr) * 128 + c4];
    }
    __syncthreads();
#pragma unroll
    for (int k = 0; k < 32; k++) {
      float4 w0 = *(const float4*)&Ws[k][colg];
      float4 w1 = *(const float4*)&Ws[k][colg + 64];
#pragma unroll
      for (int r = 0; r < 4; r++) {
        float a = As[rowg + r][k];
        acc[r][0] = fmaf(a, w0.x, acc[r][0]);
        acc[r][1] = fmaf(a, w0.y, acc[r][1]);
        acc[r][2] = fmaf(a, w0.z, acc[r][2]);
        acc[r][3] = fmaf(a, w0.w, acc[r][3]);
        acc[r][4] = fmaf(a, w1.x, acc[r][4]);
        acc[r][5] = fmaf(a, w1.y, acc[r][5]);
        acc[r][6] = fmaf(a, w1.z, acc[r][6]);
        acc[r][7] = fmaf(a, w1.w, acc[r][7]);
      }
    }
    __syncthreads();
  }
#pragma unroll
  for (int r = 0; r < 4; r++) {
    int g = row0 + rowg + r;
    if (g < N) {
      __half2 p0 = __float22half2_rn(make_float2(acc[r][0], acc[r][1]));
      __half2 p1 = __float22half2_rn(make_float2(acc[r][2], acc[r][3]));
      __half2 p2 = __float22half2_rn(make_float2(acc[r][4], acc[r][5]));
      __half2 p3 = __float22half2_rn(make_float2(acc[r][6], acc[r][7]));
      uint2 q0, q1;
      q0.x = *(unsigned*)&p0; q0.y = *(unsigned*)&p1;
      q1.x = *(unsigned*)&p2; q1.y = *(unsigned*)&p3;
      *(uint2*)&out[(size_t)g * 128 + colg] = q0;
      *(uint2*)&out[(size_t)g * 128 + colg + 64] = q1;
    }
  }
}

// ---------------- Sparse aggregation: fp16 rows in, fp32 out ----------------

__device__ __forceinline__ void acc_q(float4& a, uint2 q) {
  float2 f0 = __half22float2(*(__half2*)&q.x);
  float2 f1 = __half22float2(*(__half2*)&q.y);
  a.x += f0.x; a.y += f0.y; a.z += f1.x; a.w += f1.y;
}

__global__ __launch_bounds__(256) void k_aggregate_h(const __half* __restrict__ hin, const int* __restrict__ rp,
                                                     const int* __restrict__ ci, const float* __restrict__ c_dst,
                                                     const float* __restrict__ bias, float* __restrict__ hout, int N) {
  int v = blockIdx.x * 4 + (threadIdx.x >> 6);
  if (v >= N) return;
  int half_id = (threadIdx.x >> 5) & 1;
  int f4 = (threadIdx.x & 31) * 4;
  const __half* hb = hin + f4;
  int pe = rp[v + 1];
  int p = rp[v] + half_id;
  float4 a0 = make_float4(0.f, 0.f, 0.f, 0.f);
  float4 a1 = make_float4(0.f, 0.f, 0.f, 0.f);
  float4 a2 = make_float4(0.f, 0.f, 0.f, 0.f);
  float4 a3 = make_float4(0.f, 0.f, 0.f, 0.f);
  for (; p + 6 < pe; p += 8) {
    int u0 = ci[p];
    int u1 = ci[p + 2];
    int u2 = ci[p + 4];
    int u3 = ci[p + 6];
    uint2 q0 = *(const uint2*)(hb + (size_t)u0 * 128);
    uint2 q1 = *(const uint2*)(hb + (size_t)u1 * 128);
    uint2 q2 = *(const uint2*)(hb + (size_t)u2 * 128);
    uint2 q3 = *(const uint2*)(hb + (size_t)u3 * 128);
    acc_q(a0, q0);
    acc_q(a1, q1);
    acc_q(a2, q2);
    acc_q(a3, q3);
  }
  for (; p < pe; p += 2) {
    uint2 q = *(const uint2*)(hb + (size_t)ci[p] * 128);
    acc_q(a0, q);
  }
  a0.x += a1.x; a0.y += a1.y; a0.z += a1.z; a0.w += a1.w;
  a2.x += a3.x; a2.y += a3.y; a2.z += a3.z; a2.w += a3.w;
  a0.x += a2.x; a0.y += a2.y; a0.z += a2.z; a0.w += a2.w;
  a0.x += __shfl_xor(a0.x, 32);
  a0.y += __shfl_xor(a0.y, 32);
  a0.z += __shfl_xor(a0.z, 32);
  a0.w += __shfl_xor(a0.w, 32);
  if (half_id == 0) {
    float cd = c_dst[v];
    float4 b = *(const float4*)&bias[f4];
    float4 o;
    o.x = fmaxf(fmaf(a0.x, cd, b.x), 0.f);
    o.y = fmaxf(fmaf(a0.y, cd, b.y), 0.f);
    o.z = fmaxf(fmaf(a0.z, cd, b.z), 0.f);
    o.w = fmaxf(fmaf(a0.w, cd, b.w), 0.f);
    *(float4*)&hout[(size_t)v * 128 + f4] = o;
  }
}

// ---------------- Classifier: out[N,47] = h @ Wc + bc, register-tiled ----------------
// Block: 256 rows x 48 cols (col 47 zero-pad). Thread: 4 rows (tm+{0,64,128,192}) x 12 cols.
// hs stride 33 -> banks (tm+k)%32 distinct. Ws[32][48]: b128 at 12-float offsets = disjoint quads.

__global__ __launch_bounds__(256) void k_classifier(const float* __restrict__ h, const float* __restrict__ Wc,
                                                    const float* __restrict__ bc, float* __restrict__ out, int N) {
  __shared__ float hs[256][33];
  __shared__ float Ws[32][48];
  __shared__ float bs[48];
  int t = threadIdx.x;
  int row0 = blockIdx.x * 256;
  int tc = t & 3;          // col group: cols tc*12 .. tc*12+11
  int tm = t >> 2;         // rows tm + {0,64,128,192}
  if (t < 47) bs[t] = bc[t];
  if (t == 255) bs[47] = 0.f;

  float acc[4][12];
#pragma unroll
  for (int g = 0; g < 4; g++)
#pragma unroll
    for (int j = 0; j < 12; j++) acc[g][j] = 0.f;

  for (int kb = 0; kb < 128; kb += 32) {
#pragma unroll
    for (int i = 0; i < 8; i++) {
      int f = t + i * 256;         // 2048 float4 slots of 256x32
      int r = f >> 3;
      int c4 = (f & 7) * 4;
      int g = row0 + r;
      float4 v = make_float4(0.f, 0.f, 0.f, 0.f);
      if (g < N) v = *(const float4*)&h[(size_t)g * 128 + kb + c4];
      hs[r][c4] = v.x; hs[r][c4 + 1] = v.y; hs[r][c4 + 2] = v.z; hs[r][c4 + 3] = v.w;
    }
#pragma unroll
    for (int i = 0; i < 6; i++) {
      int f = t + i * 256;         // 1536 slots of 32x48
      int k = f / 48;
      int c = f - k * 48;
      Ws[k][c] = (c < 47) ? Wc[(size_t)(kb + k) * 47 + c] : 0.f;
    }
    __syncthreads();
#pragma unroll 4
    for (int k = 0; k < 32; k++) {
      float4 w0 = *(const float4*)&Ws[k][tc * 12];
      float4 w1 = *(const float4*)&Ws[k][tc * 12 + 4];
      float4 w2 = *(const float4*)&Ws[k][tc * 12 + 8];
      float a0 = hs[tm][k];
      float a1 = hs[tm + 64][k];
      float a2 = hs[tm + 128][k];
      float a3 = hs[tm + 192][k];
      float a[4] = {a0, a1, a2, a3};
#pragma unroll
      for (int g = 0; g < 4; g++) {
        acc[g][0] = fmaf(a[g], w0.x, acc[g][0]);
        acc[g][1] = fmaf(a[g], w0.y, acc[g][1]);
        acc[g][2] = fmaf(a[g], w0.z, acc[g][2]);
        acc[g][3] = fmaf(a[g], w0.w, acc[g][3]);
        acc[g][4] = fmaf(a[g], w1.x, acc[g][4]);
        acc[g][5] = fmaf(a[g], w1.y, acc[g][5]);
        acc[g][6] = fmaf(a[g], w1.z, acc[g][6]);
        acc[g][7] = fmaf(a[g], w1.w, acc[g][7]);
        acc[g][8] = fmaf(a[g], w2.x, acc[g][8]);
        acc[g][9] = fmaf(a[g], w2.y, acc[g][9]);
        acc[g][10] = fmaf(a[g], w2.z, acc[g][10]);
        acc[g][11] = fmaf(a[g], w2.w, acc[g][11]);
      }
    }
    __syncthreads();
  }
#pragma unroll
  for (int g = 0; g < 4; g++) {
    int r = row0 + tm + 64 * g;
    if (r < N) {
#pragma unroll
      for (int j = 0; j < 12; j++) {
        int c = tc * 12 + j;
        if (c < 47) out[(size_t)r * 47 + c] = acc[g][j] + bs[c];
      }
    }
  }
}

// ---------------- launch ----------------

extern "C" void kernel_launch(void* const* d_in, const int* in_sizes, int n_in,
                              void* d_out, int out_size, void* d_ws, size_t ws_size,
                              hipStream_t stream) {
  const float* x  = (const float*)d_in[0];
  const int* edges = (const int*)d_in[1];
  const float* W0 = (const float*)d_in[2];
  const float* b0 = (const float*)d_in[3];
  const float* W1 = (const float*)d_in[4];
  const float* b1 = (const float*)d_in[5];
  const float* Wc = (const float*)d_in[6];
  const float* bc = (const float*)d_in[7];
  float* out = (float*)d_out;

  int N = in_sizes[0] / 128;
  int E = in_sizes[1] / 2;
  const int* src = edges;
  const int* dst = edges + E;

  int NB = (N + ((1 << BSHIFT) - 1)) >> BSHIFT;   // 391 for N=100000 (<=512 required)
  int src_bits = 0;
  while ((1 << src_bits) < N) src_bits++;          // 17 for N=100000
  int per_blk = (E + PB - 1) / PB;

  char* base = (char*)d_ws;
  size_t off = 0;
  auto alloc = [&](size_t bytes) -> void* {
    void* p = base + off;
    off += (bytes + 255) & ~(size_t)255;
    return p;
  };
  float* c_src = (float*)alloc((size_t)N * 4);
  float* c_dst = (float*)alloc((size_t)N * 4);
  int* deg_out = (int*)alloc((size_t)N * 4);
  int* row_ptr = (int*)alloc((size_t)(N + 1) * 4);
  int* col_idx = (int*)alloc((size_t)E * 4);
  __half* h0h = (__half*)alloc((size_t)N * 128 * 2);   // GEMM outputs (fp16, 25.6 MB)
  float* h1 = (float*)alloc((size_t)N * 128 * 4);      // aggregate outputs (fp32)

  // build-time scratch carved out of h1 (dead until first k_aggregate writes h1)
  char* hb = (char*)h1;
  unsigned* ebuf = (unsigned*)hb;            hb += (size_t)E * 4;
  int* cntT = (int*)hb;                      hb += (size_t)NB * PB * 4;
  int* offsT = (int*)hb;                     hb += (size_t)NB * PB * 4;
  int* total = (int*)hb;                     hb += (size_t)NB * 4;
  int* bbase = (int*)hb;                     hb += (size_t)(NB + 1) * 4;

  hipMemsetAsync(deg_out, 0, (size_t)N * 4, stream);
  k_histo<<<1024, 256, 0, stream>>>(src, E, deg_out);
  k_coeffs_src<<<(N + 255) / 256, 256, 0, stream>>>(deg_out, c_src, N);

  k_count<<<PB, 256, 0, stream>>>(dst, E, per_blk, NB, cntT);
  k_scanblk<<<NB, 256, 0, stream>>>(cntT, offsT, total);
  k_scantot<<<1, 512, 0, stream>>>(total, NB, E, bbase, row_ptr, N);
  k_partition<<<PB, 256, 0, stream>>>(src, dst, E, per_blk, NB, offsT, bbase, ebuf, src_bits);
  k_finalize<<<NB, 256, 0, stream>>>(ebuf, bbase, N, src_bits, row_ptr, c_dst, col_idx);

  k_gemm128_h<<<(N + 63) / 64, 256, 0, stream>>>(x, W0, c_src, h0h, N);
  k_aggregate_h<<<(N + 3) / 4, 256, 0, stream>>>(h0h, row_ptr, col_idx, c_dst, b0, h1, N);
  k_gemm128_h<<<(N + 63) / 64, 256, 0, stream>>>(h1, W1, c_src, h0h, N);
  k_aggregate_h<<<(N + 3) / 4, 256, 0, stream>>>(h0h, row_ptr, col_idx, c_dst, b1, h1, N);
  k_classifier<<<(N + 255) / 256, 256, 0, stream>>>(h1, Wc, bc, out, N);
}

// Round 6
// 426.946 us; speedup vs baseline: 1.9767x; 1.1105x over previous
//
#include <hip/hip_runtime.h>
#include <hip/hip_fp16.h>

// GCN: h0 = relu(c_dst ⊙ Agg(c_src ⊙ x @ W0) + b0); h1 = same with W1; out = h1 @ Wc + bc
// R5: dense 128x128 transforms moved to MFMA f16 (fp32 accumulate). W staged to LDS as
//     Wt[n][k] fp16 (stride 136 halves -> bank-balanced b128 frag reads); A read from
//     global fp32 + scaled + converted in-register; W passed as MFMA A-operand so the
//     D layout gives 4 consecutive n per lane (pack2 -> 8B store, no LDS round trip).

#define PB 256          // partition blocks
#define BSHIFT 8        // bucket = dst >> 8 (256 nodes/bucket)

typedef _Float16 f16x8 __attribute__((ext_vector_type(8)));
typedef float f32x4 __attribute__((ext_vector_type(4)));

// ---------------- out-degree histogram (for c_src) ----------------

__global__ __launch_bounds__(256) void k_histo(const int* __restrict__ src, int E, int* __restrict__ dout) {
  int stride = gridDim.x * blockDim.x;
  for (int e = blockIdx.x * blockDim.x + threadIdx.x; e < E; e += stride)
    atomicAdd(&dout[src[e]], 1);
}

__global__ __launch_bounds__(256) void k_coeffs_src(const int* __restrict__ dout, float* __restrict__ c_src, int N) {
  int i = blockIdx.x * blockDim.x + threadIdx.x;
  if (i < N) c_src[i] = rsqrtf((float)max(dout[i], 1));
}

// ---------------- Phase A: bucket counts ----------------

__global__ __launch_bounds__(256) void k_count(const int* __restrict__ dst, int E, int per_blk, int NB,
                                               int* __restrict__ cntT) {
  __shared__ int cnt[512];
  for (int i = threadIdx.x; i < NB; i += 256) cnt[i] = 0;
  __syncthreads();
  int e0 = blockIdx.x * per_blk, e1 = min(E, e0 + per_blk);
  for (int e = e0 + threadIdx.x; e < e1; e += 256) atomicAdd(&cnt[dst[e] >> BSHIFT], 1);
  __syncthreads();
  for (int i = threadIdx.x; i < NB; i += 256) cntT[i * PB + blockIdx.x] = cnt[i];
}

__global__ __launch_bounds__(256) void k_scanblk(const int* __restrict__ cntT, int* __restrict__ offsT,
                                                 int* __restrict__ total) {
  __shared__ int s[256];
  int b = blockIdx.x, t = threadIdx.x;
  int v = cntT[b * PB + t];
  s[t] = v;
  __syncthreads();
  for (int off = 1; off < 256; off <<= 1) {
    int x = (t >= off) ? s[t - off] : 0;
    __syncthreads();
    s[t] += x;
    __syncthreads();
  }
  offsT[b * PB + t] = s[t] - v;
  if (t == 255) total[b] = s[255];
}

__global__ __launch_bounds__(512) void k_scantot(const int* __restrict__ total, int NB, int E,
                                                 int* __restrict__ bbase, int* __restrict__ row_ptr, int N) {
  __shared__ int s[512];
  int t = threadIdx.x;
  int v = (t < NB) ? total[t] : 0;
  s[t] = v;
  __syncthreads();
  for (int off = 1; off < 512; off <<= 1) {
    int x = (t >= off) ? s[t - off] : 0;
    __syncthreads();
    s[t] += x;
    __syncthreads();
  }
  if (t < NB) bbase[t] = s[t] - v;
  if (t == 0) { bbase[NB] = E; row_ptr[N] = E; }
}

// ---------------- Phase A: partition scatter ----------------

__global__ __launch_bounds__(256) void k_partition(const int* __restrict__ src, const int* __restrict__ dst,
                                                   int E, int per_blk, int NB,
                                                   const int* __restrict__ offsT, const int* __restrict__ bbase,
                                                   unsigned* __restrict__ ebuf, int src_bits) {
  __shared__ int cur[512];
  for (int i = threadIdx.x; i < NB; i += 256) cur[i] = bbase[i] + offsT[i * PB + blockIdx.x];
  __syncthreads();
  int e0 = blockIdx.x * per_blk, e1 = min(E, e0 + per_blk);
  for (int e = e0 + threadIdx.x; e < e1; e += 256) {
    int d = dst[e], s = src[e];
    int pos = atomicAdd(&cur[d >> BSHIFT], 1);
    ebuf[pos] = ((unsigned)(d & ((1 << BSHIFT) - 1)) << src_bits) | (unsigned)s;
  }
}

// ---------------- Phase B: per-bucket finalize -> row_ptr, c_dst, col_idx ----------------

__global__ __launch_bounds__(256) void k_finalize(const unsigned* __restrict__ ebuf, const int* __restrict__ bbase,
                                                  int N, int src_bits, int* __restrict__ row_ptr,
                                                  float* __restrict__ c_dst, int* __restrict__ col_idx) {
  __shared__ int cnt[256];
  __shared__ int s[256];
  __shared__ int cur[256];
  int b = blockIdx.x, t = threadIdx.x;
  int r0 = bbase[b], r1 = bbase[b + 1];
  cnt[t] = 0;
  __syncthreads();
  for (int i = r0 + t; i < r1; i += 256) atomicAdd(&cnt[ebuf[i] >> src_bits], 1);
  __syncthreads();
  int v = cnt[t];
  s[t] = v;
  __syncthreads();
  for (int off = 1; off < 256; off <<= 1) {
    int x = (t >= off) ? s[t - off] : 0;
    __syncthreads();
    s[t] += x;
    __syncthreads();
  }
  int ex = s[t] - v;
  cur[t] = ex;
  int node = (b << BSHIFT) + t;
  if (node < N) {
    row_ptr[node] = r0 + ex;
    c_dst[node] = rsqrtf((float)max(v, 1));
  }
  __syncthreads();
  unsigned smask = (1u << src_bits) - 1u;
  for (int i = r0 + t; i < r1; i += 256) {
    unsigned e = ebuf[i];
    int pos = r0 + atomicAdd(&cur[e >> src_bits], 1);
    col_idx[pos] = (int)(e & smask);
  }
}

// ---------------- MFMA GEMM: out[m][n] = (sum_k A[m][k]*sc[m]*W[k][n]) -> fp16 ----------------
// Block: 128 rows. Wave: 32 rows (2 strips of 16). K=128, Ncols=128 (8 tiles of 16).
// mfma(A-op = Wt tile, B-op = A rows): D[i=n][j=m]; lane holds m=m0+li, n = nt*16+q*4+reg.

__global__ __launch_bounds__(256) void k_gemm_mfma(const float* __restrict__ A, const float* __restrict__ W,
                                                   const float* __restrict__ scale, __half* __restrict__ out, int N) {
  __shared__ _Float16 Wt[128][136];
  int t = threadIdx.x;
  // stage W -> Wt[n][k] fp16. thread t: n-low = t&15 (coalesced 64B), kp-low = t>>4.
  {
    int nlow = t & 15;
    int kplow = t >> 4;
#pragma unroll
    for (int j = 0; j < 32; j++) {
      int n = nlow + 16 * (j & 7);
      int kp = kplow + 16 * (j >> 3);
      float w0 = W[(size_t)(2 * kp) * 128 + n];
      float w1 = W[(size_t)(2 * kp + 1) * 128 + n];
      __half2 h2 = __floats2half2_rn(w0, w1);
      *(__half2*)&Wt[n][2 * kp] = h2;
    }
  }
  __syncthreads();

  int wave = t >> 6;
  int lane = t & 63;
  int li = lane & 15;
  int q = lane >> 4;
  int m0 = blockIdx.x * 128 + wave * 32;

  int mrow[2];
  float csc[2];
  bool mok[2];
  const float* arow[2];
#pragma unroll
  for (int s = 0; s < 2; s++) {
    mrow[s] = m0 + s * 16 + li;
    mok[s] = mrow[s] < N;
    csc[s] = mok[s] ? scale[mrow[s]] : 0.f;
    arow[s] = A + (size_t)(mok[s] ? mrow[s] : 0) * 128;
  }

  f32x4 acc[2][8];
#pragma unroll
  for (int s = 0; s < 2; s++)
#pragma unroll
    for (int nt = 0; nt < 8; nt++) acc[s][nt] = (f32x4){0.f, 0.f, 0.f, 0.f};

#pragma unroll
  for (int kc = 0; kc < 128; kc += 32) {
    f16x8 af[2];
#pragma unroll
    for (int s = 0; s < 2; s++) {
      float4 a0 = make_float4(0.f, 0.f, 0.f, 0.f), a1 = a0;
      if (mok[s]) {
        a0 = *(const float4*)(arow[s] + kc + q * 8);
        a1 = *(const float4*)(arow[s] + kc + q * 8 + 4);
      }
      f16x8 v;
      v[0] = (_Float16)(a0.x * csc[s]);
      v[1] = (_Float16)(a0.y * csc[s]);
      v[2] = (_Float16)(a0.z * csc[s]);
      v[3] = (_Float16)(a0.w * csc[s]);
      v[4] = (_Float16)(a1.x * csc[s]);
      v[5] = (_Float16)(a1.y * csc[s]);
      v[6] = (_Float16)(a1.z * csc[s]);
      v[7] = (_Float16)(a1.w * csc[s]);
      af[s] = v;
    }
#pragma unroll
    for (int nt = 0; nt < 8; nt++) {
      f16x8 wf = *(const f16x8*)&Wt[nt * 16 + li][kc + q * 8];
      acc[0][nt] = __builtin_amdgcn_mfma_f32_16x16x32_f16(wf, af[0], acc[0][nt], 0, 0, 0);
      acc[1][nt] = __builtin_amdgcn_mfma_f32_16x16x32_f16(wf, af[1], acc[1][nt], 0, 0, 0);
    }
  }

#pragma unroll
  for (int s = 0; s < 2; s++) {
    if (!mok[s]) continue;
    size_t rb = (size_t)mrow[s] * 128;
#pragma unroll
    for (int nt = 0; nt < 8; nt++) {
      __half2 p0 = __floats2half2_rn(acc[s][nt][0], acc[s][nt][1]);
      __half2 p1 = __floats2half2_rn(acc[s][nt][2], acc[s][nt][3]);
      uint2 qv;
      qv.x = *(unsigned*)&p0;
      qv.y = *(unsigned*)&p1;
      *(uint2*)&out[rb + nt * 16 + q * 4] = qv;
    }
  }
}

// ---------------- Sparse aggregation: fp16 rows in, fp32 out ----------------

__device__ __forceinline__ void acc_q(float4& a, uint2 q) {
  float2 f0 = __half22float2(*(__half2*)&q.x);
  float2 f1 = __half22float2(*(__half2*)&q.y);
  a.x += f0.x; a.y += f0.y; a.z += f1.x; a.w += f1.y;
}

__global__ __launch_bounds__(256) void k_aggregate_h(const __half* __restrict__ hin, const int* __restrict__ rp,
                                                     const int* __restrict__ ci, const float* __restrict__ c_dst,
                                                     const float* __restrict__ bias, float* __restrict__ hout, int N) {
  int v = blockIdx.x * 4 + (threadIdx.x >> 6);
  if (v >= N) return;
  int half_id = (threadIdx.x >> 5) & 1;
  int f4 = (threadIdx.x & 31) * 4;
  const __half* hb = hin + f4;
  int pe = rp[v + 1];
  int p = rp[v] + half_id;
  float4 a0 = make_float4(0.f, 0.f, 0.f, 0.f);
  float4 a1 = make_float4(0.f, 0.f, 0.f, 0.f);
  float4 a2 = make_float4(0.f, 0.f, 0.f, 0.f);
  float4 a3 = make_float4(0.f, 0.f, 0.f, 0.f);
  for (; p + 6 < pe; p += 8) {
    int u0 = ci[p];
    int u1 = ci[p + 2];
    int u2 = ci[p + 4];
    int u3 = ci[p + 6];
    uint2 q0 = *(const uint2*)(hb + (size_t)u0 * 128);
    uint2 q1 = *(const uint2*)(hb + (size_t)u1 * 128);
    uint2 q2 = *(const uint2*)(hb + (size_t)u2 * 128);
    uint2 q3 = *(const uint2*)(hb + (size_t)u3 * 128);
    acc_q(a0, q0);
    acc_q(a1, q1);
    acc_q(a2, q2);
    acc_q(a3, q3);
  }
  for (; p < pe; p += 2) {
    uint2 q = *(const uint2*)(hb + (size_t)ci[p] * 128);
    acc_q(a0, q);
  }
  a0.x += a1.x; a0.y += a1.y; a0.z += a1.z; a0.w += a1.w;
  a2.x += a3.x; a2.y += a3.y; a2.z += a3.z; a2.w += a3.w;
  a0.x += a2.x; a0.y += a2.y; a0.z += a2.z; a0.w += a2.w;
  a0.x += __shfl_xor(a0.x, 32);
  a0.y += __shfl_xor(a0.y, 32);
  a0.z += __shfl_xor(a0.z, 32);
  a0.w += __shfl_xor(a0.w, 32);
  if (half_id == 0) {
    float cd = c_dst[v];
    float4 b = *(const float4*)&bias[f4];
    float4 o;
    o.x = fmaxf(fmaf(a0.x, cd, b.x), 0.f);
    o.y = fmaxf(fmaf(a0.y, cd, b.y), 0.f);
    o.z = fmaxf(fmaf(a0.z, cd, b.z), 0.f);
    o.w = fmaxf(fmaf(a0.w, cd, b.w), 0.f);
    *(float4*)&hout[(size_t)v * 128 + f4] = o;
  }
}

// ---------------- Classifier: out[N,47] = h @ Wc + bc, register-tiled ----------------

__global__ __launch_bounds__(256) void k_classifier(const float* __restrict__ h, const float* __restrict__ Wc,
                                                    const float* __restrict__ bc, float* __restrict__ out, int N) {
  __shared__ float hs[256][33];
  __shared__ float Ws[32][48];
  __shared__ float bs[48];
  int t = threadIdx.x;
  int row0 = blockIdx.x * 256;
  int tc = t & 3;
  int tm = t >> 2;
  if (t < 47) bs[t] = bc[t];
  if (t == 255) bs[47] = 0.f;

  float acc[4][12];
#pragma unroll
  for (int g = 0; g < 4; g++)
#pragma unroll
    for (int j = 0; j < 12; j++) acc[g][j] = 0.f;

  for (int kb = 0; kb < 128; kb += 32) {
#pragma unroll
    for (int i = 0; i < 8; i++) {
      int f = t + i * 256;
      int r = f >> 3;
      int c4 = (f & 7) * 4;
      int g = row0 + r;
      float4 v = make_float4(0.f, 0.f, 0.f, 0.f);
      if (g < N) v = *(const float4*)&h[(size_t)g * 128 + kb + c4];
      hs[r][c4] = v.x; hs[r][c4 + 1] = v.y; hs[r][c4 + 2] = v.z; hs[r][c4 + 3] = v.w;
    }
#pragma unroll
    for (int i = 0; i < 6; i++) {
      int f = t + i * 256;
      int k = f / 48;
      int c = f - k * 48;
      Ws[k][c] = (c < 47) ? Wc[(size_t)(kb + k) * 47 + c] : 0.f;
    }
    __syncthreads();
#pragma unroll 4
    for (int k = 0; k < 32; k++) {
      float4 w0 = *(const float4*)&Ws[k][tc * 12];
      float4 w1 = *(const float4*)&Ws[k][tc * 12 + 4];
      float4 w2 = *(const float4*)&Ws[k][tc * 12 + 8];
      float a0 = hs[tm][k];
      float a1 = hs[tm + 64][k];
      float a2 = hs[tm + 128][k];
      float a3 = hs[tm + 192][k];
      float a[4] = {a0, a1, a2, a3};
#pragma unroll
      for (int g = 0; g < 4; g++) {
        acc[g][0] = fmaf(a[g], w0.x, acc[g][0]);
        acc[g][1] = fmaf(a[g], w0.y, acc[g][1]);
        acc[g][2] = fmaf(a[g], w0.z, acc[g][2]);
        acc[g][3] = fmaf(a[g], w0.w, acc[g][3]);
        acc[g][4] = fmaf(a[g], w1.x, acc[g][4]);
        acc[g][5] = fmaf(a[g], w1.y, acc[g][5]);
        acc[g][6] = fmaf(a[g], w1.z, acc[g][6]);
        acc[g][7] = fmaf(a[g], w1.w, acc[g][7]);
        acc[g][8] = fmaf(a[g], w2.x, acc[g][8]);
        acc[g][9] = fmaf(a[g], w2.y, acc[g][9]);
        acc[g][10] = fmaf(a[g], w2.z, acc[g][10]);
        acc[g][11] = fmaf(a[g], w2.w, acc[g][11]);
      }
    }
    __syncthreads();
  }
#pragma unroll
  for (int g = 0; g < 4; g++) {
    int r = row0 + tm + 64 * g;
    if (r < N) {
#pragma unroll
      for (int j = 0; j < 12; j++) {
        int c = tc * 12 + j;
        if (c < 47) out[(size_t)r * 47 + c] = acc[g][j] + bs[c];
      }
    }
  }
}

// ---------------- launch ----------------

extern "C" void kernel_launch(void* const* d_in, const int* in_sizes, int n_in,
                              void* d_out, int out_size, void* d_ws, size_t ws_size,
                              hipStream_t stream) {
  const float* x  = (const float*)d_in[0];
  const int* edges = (const int*)d_in[1];
  const float* W0 = (const float*)d_in[2];
  const float* b0 = (const float*)d_in[3];
  const float* W1 = (const float*)d_in[4];
  const float* b1 = (const float*)d_in[5];
  const float* Wc = (const float*)d_in[6];
  const float* bc = (const float*)d_in[7];
  float* out = (float*)d_out;

  int N = in_sizes[0] / 128;
  int E = in_sizes[1] / 2;
  const int* src = edges;
  const int* dst = edges + E;

  int NB = (N + ((1 << BSHIFT) - 1)) >> BSHIFT;
  int src_bits = 0;
  while ((1 << src_bits) < N) src_bits++;
  int per_blk = (E + PB - 1) / PB;

  char* base = (char*)d_ws;
  size_t off = 0;
  auto alloc = [&](size_t bytes) -> void* {
    void* p = base + off;
    off += (bytes + 255) & ~(size_t)255;
    return p;
  };
  float* c_src = (float*)alloc((size_t)N * 4);
  float* c_dst = (float*)alloc((size_t)N * 4);
  int* deg_out = (int*)alloc((size_t)N * 4);
  int* row_ptr = (int*)alloc((size_t)(N + 1) * 4);
  int* col_idx = (int*)alloc((size_t)E * 4);
  __half* h0h = (__half*)alloc((size_t)N * 128 * 2);   // GEMM outputs (fp16, 25.6 MB)
  float* h1 = (float*)alloc((size_t)N * 128 * 4);      // aggregate outputs (fp32)

  // build-time scratch carved out of h1 (dead until first k_aggregate writes h1)
  char* hb = (char*)h1;
  unsigned* ebuf = (unsigned*)hb;            hb += (size_t)E * 4;
  int* cntT = (int*)hb;                      hb += (size_t)NB * PB * 4;
  int* offsT = (int*)hb;                     hb += (size_t)NB * PB * 4;
  int* total = (int*)hb;                     hb += (size_t)NB * 4;
  int* bbase = (int*)hb;                     hb += (size_t)(NB + 1) * 4;

  hipMemsetAsync(deg_out, 0, (size_t)N * 4, stream);
  k_histo<<<1024, 256, 0, stream>>>(src, E, deg_out);
  k_coeffs_src<<<(N + 255) / 256, 256, 0, stream>>>(deg_out, c_src, N);

  k_count<<<PB, 256, 0, stream>>>(dst, E, per_blk, NB, cntT);
  k_scanblk<<<NB, 256, 0, stream>>>(cntT, offsT, total);
  k_scantot<<<1, 512, 0, stream>>>(total, NB, E, bbase, row_ptr, N);
  k_partition<<<PB, 256, 0, stream>>>(src, dst, E, per_blk, NB, offsT, bbase, ebuf, src_bits);
  k_finalize<<<NB, 256, 0, stream>>>(ebuf, bbase, N, src_bits, row_ptr, c_dst, col_idx);

  k_gemm_mfma<<<(N + 127) / 128, 256, 0, stream>>>(x, W0, c_src, h0h, N);
  k_aggregate_h<<<(N + 3) / 4, 256, 0, stream>>>(h0h, row_ptr, col_idx, c_dst, b0, h1, N);
  k_gemm_mfma<<<(N + 127) / 128, 256, 0, stream>>>(h1, W1, c_src, h0h, N);
  k_aggregate_h<<<(N + 3) / 4, 256, 0, stream>>>(h0h, row_ptr, col_idx, c_dst, b1, h1, N);
  k_classifier<<<(N + 255) / 256, 256, 0, stream>>>(h1, Wc, bc, out, N);
}

// Round 7
// 417.303 us; speedup vs baseline: 2.0224x; 1.0231x over previous
//
#include <hip/hip_runtime.h>
#include <hip/hip_fp16.h>

// GCN: h0 = relu(c_dst ⊙ Agg(c_src ⊙ x @ W0) + b0); h1 = same with W1; out = h1 @ Wc + bc
// R6: (1) MFMA GEMM stages W once per block and computes 2 row-strips (grid 391) —
//     W staging was ~half the per-block work at 782 blocks.
//     (2) aggregate: contiguous per-half edge ranges, unroll 8 edges/half, fp16 pairwise
//     pre-add (__hadd2) before fp32 accumulate -> ~2x VALU cut, +MLP.

#define PB 256          // partition blocks
#define BSHIFT 8        // bucket = dst >> 8 (256 nodes/bucket)

typedef _Float16 f16x8 __attribute__((ext_vector_type(8)));
typedef float f32x4 __attribute__((ext_vector_type(4)));

// ---------------- out-degree histogram (for c_src) ----------------

__global__ __launch_bounds__(256) void k_histo(const int* __restrict__ src, int E, int* __restrict__ dout) {
  int stride = gridDim.x * blockDim.x;
  for (int e = blockIdx.x * blockDim.x + threadIdx.x; e < E; e += stride)
    atomicAdd(&dout[src[e]], 1);
}

__global__ __launch_bounds__(256) void k_coeffs_src(const int* __restrict__ dout, float* __restrict__ c_src, int N) {
  int i = blockIdx.x * blockDim.x + threadIdx.x;
  if (i < N) c_src[i] = rsqrtf((float)max(dout[i], 1));
}

// ---------------- Phase A: bucket counts ----------------

__global__ __launch_bounds__(256) void k_count(const int* __restrict__ dst, int E, int per_blk, int NB,
                                               int* __restrict__ cntT) {
  __shared__ int cnt[512];
  for (int i = threadIdx.x; i < NB; i += 256) cnt[i] = 0;
  __syncthreads();
  int e0 = blockIdx.x * per_blk, e1 = min(E, e0 + per_blk);
  for (int e = e0 + threadIdx.x; e < e1; e += 256) atomicAdd(&cnt[dst[e] >> BSHIFT], 1);
  __syncthreads();
  for (int i = threadIdx.x; i < NB; i += 256) cntT[i * PB + blockIdx.x] = cnt[i];
}

__global__ __launch_bounds__(256) void k_scanblk(const int* __restrict__ cntT, int* __restrict__ offsT,
                                                 int* __restrict__ total) {
  __shared__ int s[256];
  int b = blockIdx.x, t = threadIdx.x;
  int v = cntT[b * PB + t];
  s[t] = v;
  __syncthreads();
  for (int off = 1; off < 256; off <<= 1) {
    int x = (t >= off) ? s[t - off] : 0;
    __syncthreads();
    s[t] += x;
    __syncthreads();
  }
  offsT[b * PB + t] = s[t] - v;
  if (t == 255) total[b] = s[255];
}

__global__ __launch_bounds__(512) void k_scantot(const int* __restrict__ total, int NB, int E,
                                                 int* __restrict__ bbase, int* __restrict__ row_ptr, int N) {
  __shared__ int s[512];
  int t = threadIdx.x;
  int v = (t < NB) ? total[t] : 0;
  s[t] = v;
  __syncthreads();
  for (int off = 1; off < 512; off <<= 1) {
    int x = (t >= off) ? s[t - off] : 0;
    __syncthreads();
    s[t] += x;
    __syncthreads();
  }
  if (t < NB) bbase[t] = s[t] - v;
  if (t == 0) { bbase[NB] = E; row_ptr[N] = E; }
}

// ---------------- Phase A: partition scatter ----------------

__global__ __launch_bounds__(256) void k_partition(const int* __restrict__ src, const int* __restrict__ dst,
                                                   int E, int per_blk, int NB,
                                                   const int* __restrict__ offsT, const int* __restrict__ bbase,
                                                   unsigned* __restrict__ ebuf, int src_bits) {
  __shared__ int cur[512];
  for (int i = threadIdx.x; i < NB; i += 256) cur[i] = bbase[i] + offsT[i * PB + blockIdx.x];
  __syncthreads();
  int e0 = blockIdx.x * per_blk, e1 = min(E, e0 + per_blk);
  for (int e = e0 + threadIdx.x; e < e1; e += 256) {
    int d = dst[e], s = src[e];
    int pos = atomicAdd(&cur[d >> BSHIFT], 1);
    ebuf[pos] = ((unsigned)(d & ((1 << BSHIFT) - 1)) << src_bits) | (unsigned)s;
  }
}

// ---------------- Phase B: per-bucket finalize -> row_ptr, c_dst, col_idx ----------------

__global__ __launch_bounds__(256) void k_finalize(const unsigned* __restrict__ ebuf, const int* __restrict__ bbase,
                                                  int N, int src_bits, int* __restrict__ row_ptr,
                                                  float* __restrict__ c_dst, int* __restrict__ col_idx) {
  __shared__ int cnt[256];
  __shared__ int s[256];
  __shared__ int cur[256];
  int b = blockIdx.x, t = threadIdx.x;
  int r0 = bbase[b], r1 = bbase[b + 1];
  cnt[t] = 0;
  __syncthreads();
  for (int i = r0 + t; i < r1; i += 256) atomicAdd(&cnt[ebuf[i] >> src_bits], 1);
  __syncthreads();
  int v = cnt[t];
  s[t] = v;
  __syncthreads();
  for (int off = 1; off < 256; off <<= 1) {
    int x = (t >= off) ? s[t - off] : 0;
    __syncthreads();
    s[t] += x;
    __syncthreads();
  }
  int ex = s[t] - v;
  cur[t] = ex;
  int node = (b << BSHIFT) + t;
  if (node < N) {
    row_ptr[node] = r0 + ex;
    c_dst[node] = rsqrtf((float)max(v, 1));
  }
  __syncthreads();
  unsigned smask = (1u << src_bits) - 1u;
  for (int i = r0 + t; i < r1; i += 256) {
    unsigned e = ebuf[i];
    int pos = r0 + atomicAdd(&cur[e >> src_bits], 1);
    col_idx[pos] = (int)(e & smask);
  }
}

// ---------------- MFMA GEMM: out[m][n] = (sum_k A[m][k]*sc[m]*W[k][n]) -> fp16 ----------------
// Block stages W once (Wt[n][k] fp16, stride 136), then computes 2 strips of 128 rows.
// mfma(A-op = Wt tile, B-op = A rows): lane holds m=m0+li, n = nt*16+q*4+reg -> 8B stores.

__global__ __launch_bounds__(256) void k_gemm_mfma(const float* __restrict__ A, const float* __restrict__ W,
                                                   const float* __restrict__ scale, __half* __restrict__ out, int N) {
  __shared__ _Float16 Wt[128][136];
  int t = threadIdx.x;
  {
    int nlow = t & 15;
    int kplow = t >> 4;
#pragma unroll
    for (int j = 0; j < 32; j++) {
      int n = nlow + 16 * (j & 7);
      int kp = kplow + 16 * (j >> 3);
      float w0 = W[(size_t)(2 * kp) * 128 + n];
      float w1 = W[(size_t)(2 * kp + 1) * 128 + n];
      __half2 h2 = __floats2half2_rn(w0, w1);
      *(__half2*)&Wt[n][2 * kp] = h2;
    }
  }
  __syncthreads();

  int wave = t >> 6;
  int lane = t & 63;
  int li = lane & 15;
  int q = lane >> 4;

#pragma unroll
  for (int s2 = 0; s2 < 2; s2++) {
    int m0 = (blockIdx.x * 2 + s2) * 128 + wave * 32;
    if (m0 >= N) break;

    int mrow[2];
    float csc[2];
    bool mok[2];
    const float* arow[2];
#pragma unroll
    for (int s = 0; s < 2; s++) {
      mrow[s] = m0 + s * 16 + li;
      mok[s] = mrow[s] < N;
      csc[s] = mok[s] ? scale[mrow[s]] : 0.f;
      arow[s] = A + (size_t)(mok[s] ? mrow[s] : 0) * 128;
    }

    f32x4 acc[2][8];
#pragma unroll
    for (int s = 0; s < 2; s++)
#pragma unroll
      for (int nt = 0; nt < 8; nt++) acc[s][nt] = (f32x4){0.f, 0.f, 0.f, 0.f};

#pragma unroll
    for (int kc = 0; kc < 128; kc += 32) {
      f16x8 af[2];
#pragma unroll
      for (int s = 0; s < 2; s++) {
        float4 a0 = make_float4(0.f, 0.f, 0.f, 0.f), a1 = a0;
        if (mok[s]) {
          a0 = *(const float4*)(arow[s] + kc + q * 8);
          a1 = *(const float4*)(arow[s] + kc + q * 8 + 4);
        }
        f16x8 v;
        v[0] = (_Float16)(a0.x * csc[s]);
        v[1] = (_Float16)(a0.y * csc[s]);
        v[2] = (_Float16)(a0.z * csc[s]);
        v[3] = (_Float16)(a0.w * csc[s]);
        v[4] = (_Float16)(a1.x * csc[s]);
        v[5] = (_Float16)(a1.y * csc[s]);
        v[6] = (_Float16)(a1.z * csc[s]);
        v[7] = (_Float16)(a1.w * csc[s]);
        af[s] = v;
      }
#pragma unroll
      for (int nt = 0; nt < 8; nt++) {
        f16x8 wf = *(const f16x8*)&Wt[nt * 16 + li][kc + q * 8];
        acc[0][nt] = __builtin_amdgcn_mfma_f32_16x16x32_f16(wf, af[0], acc[0][nt], 0, 0, 0);
        acc[1][nt] = __builtin_amdgcn_mfma_f32_16x16x32_f16(wf, af[1], acc[1][nt], 0, 0, 0);
      }
    }

#pragma unroll
    for (int s = 0; s < 2; s++) {
      if (!mok[s]) continue;
      size_t rb = (size_t)mrow[s] * 128;
#pragma unroll
      for (int nt = 0; nt < 8; nt++) {
        __half2 p0 = __floats2half2_rn(acc[s][nt][0], acc[s][nt][1]);
        __half2 p1 = __floats2half2_rn(acc[s][nt][2], acc[s][nt][3]);
        uint2 qv;
        qv.x = *(unsigned*)&p0;
        qv.y = *(unsigned*)&p1;
        *(uint2*)&out[rb + nt * 16 + q * 4] = qv;
      }
    }
  }
}

// ---------------- Sparse aggregation: fp16 rows in, fp32 out ----------------
// Wave per node; half-waves take contiguous sub-ranges; unroll 8 edges/half with
// fp16 pairwise pre-add (1 ulp) before fp32 accumulate.

__device__ __forceinline__ void acc_pair(float4& a, uint2 qa, uint2 qb) {
  __half2 s0 = __hadd2(*(__half2*)&qa.x, *(__half2*)&qb.x);
  __half2 s1 = __hadd2(*(__half2*)&qa.y, *(__half2*)&qb.y);
  float2 f0 = __half22float2(s0);
  float2 f1 = __half22float2(s1);
  a.x += f0.x; a.y += f0.y; a.z += f1.x; a.w += f1.y;
}

__device__ __forceinline__ void acc_one(float4& a, uint2 q) {
  float2 f0 = __half22float2(*(__half2*)&q.x);
  float2 f1 = __half22float2(*(__half2*)&q.y);
  a.x += f0.x; a.y += f0.y; a.z += f1.x; a.w += f1.y;
}

__global__ __launch_bounds__(256) void k_aggregate_h(const __half* __restrict__ hin, const int* __restrict__ rp,
                                                     const int* __restrict__ ci, const float* __restrict__ c_dst,
                                                     const float* __restrict__ bias, float* __restrict__ hout, int N) {
  int v = blockIdx.x * 4 + (threadIdx.x >> 6);
  if (v >= N) return;
  int half_id = (threadIdx.x >> 5) & 1;
  int f4 = (threadIdx.x & 31) * 4;
  const __half* hb = hin + f4;
  int p0 = rp[v], pe = rp[v + 1];
  int mid = p0 + ((pe - p0 + 1) >> 1);
  int p = half_id ? mid : p0;
  int pend = half_id ? pe : mid;
  float4 a0 = make_float4(0.f, 0.f, 0.f, 0.f);
  float4 a1 = make_float4(0.f, 0.f, 0.f, 0.f);
  float4 a2 = make_float4(0.f, 0.f, 0.f, 0.f);
  float4 a3 = make_float4(0.f, 0.f, 0.f, 0.f);
  for (; p + 7 < pend; p += 8) {
    int u0 = ci[p];
    int u1 = ci[p + 1];
    int u2 = ci[p + 2];
    int u3 = ci[p + 3];
    int u4 = ci[p + 4];
    int u5 = ci[p + 5];
    int u6 = ci[p + 6];
    int u7 = ci[p + 7];
    uint2 q0 = *(const uint2*)(hb + (size_t)u0 * 128);
    uint2 q1 = *(const uint2*)(hb + (size_t)u1 * 128);
    uint2 q2 = *(const uint2*)(hb + (size_t)u2 * 128);
    uint2 q3 = *(const uint2*)(hb + (size_t)u3 * 128);
    uint2 q4 = *(const uint2*)(hb + (size_t)u4 * 128);
    uint2 q5 = *(const uint2*)(hb + (size_t)u5 * 128);
    uint2 q6 = *(const uint2*)(hb + (size_t)u6 * 128);
    uint2 q7 = *(const uint2*)(hb + (size_t)u7 * 128);
    acc_pair(a0, q0, q1);
    acc_pair(a1, q2, q3);
    acc_pair(a2, q4, q5);
    acc_pair(a3, q6, q7);
  }
  for (; p + 1 < pend; p += 2) {
    int u0 = ci[p];
    int u1 = ci[p + 1];
    uint2 q0 = *(const uint2*)(hb + (size_t)u0 * 128);
    uint2 q1 = *(const uint2*)(hb + (size_t)u1 * 128);
    acc_pair(a0, q0, q1);
  }
  if (p < pend) {
    uint2 q = *(const uint2*)(hb + (size_t)ci[p] * 128);
    acc_one(a0, q);
  }
  a0.x += a1.x; a0.y += a1.y; a0.z += a1.z; a0.w += a1.w;
  a2.x += a3.x; a2.y += a3.y; a2.z += a3.z; a2.w += a3.w;
  a0.x += a2.x; a0.y += a2.y; a0.z += a2.z; a0.w += a2.w;
  a0.x += __shfl_xor(a0.x, 32);
  a0.y += __shfl_xor(a0.y, 32);
  a0.z += __shfl_xor(a0.z, 32);
  a0.w += __shfl_xor(a0.w, 32);
  if (half_id == 0) {
    float cd = c_dst[v];
    float4 b = *(const float4*)&bias[f4];
    float4 o;
    o.x = fmaxf(fmaf(a0.x, cd, b.x), 0.f);
    o.y = fmaxf(fmaf(a0.y, cd, b.y), 0.f);
    o.z = fmaxf(fmaf(a0.z, cd, b.z), 0.f);
    o.w = fmaxf(fmaf(a0.w, cd, b.w), 0.f);
    *(float4*)&hout[(size_t)v * 128 + f4] = o;
  }
}

// ---------------- Classifier: out[N,47] = h @ Wc + bc, register-tiled ----------------

__global__ __launch_bounds__(256) void k_classifier(const float* __restrict__ h, const float* __restrict__ Wc,
                                                    const float* __restrict__ bc, float* __restrict__ out, int N) {
  __shared__ float hs[256][33];
  __shared__ float Ws[32][48];
  __shared__ float bs[48];
  int t = threadIdx.x;
  int row0 = blockIdx.x * 256;
  int tc = t & 3;
  int tm = t >> 2;
  if (t < 47) bs[t] = bc[t];
  if (t == 255) bs[47] = 0.f;

  float acc[4][12];
#pragma unroll
  for (int g = 0; g < 4; g++)
#pragma unroll
    for (int j = 0; j < 12; j++) acc[g][j] = 0.f;

  for (int kb = 0; kb < 128; kb += 32) {
#pragma unroll
    for (int i = 0; i < 8; i++) {
      int f = t + i * 256;
      int r = f >> 3;
      int c4 = (f & 7) * 4;
      int g = row0 + r;
      float4 v = make_float4(0.f, 0.f, 0.f, 0.f);
      if (g < N) v = *(const float4*)&h[(size_t)g * 128 + kb + c4];
      hs[r][c4] = v.x; hs[r][c4 + 1] = v.y; hs[r][c4 + 2] = v.z; hs[r][c4 + 3] = v.w;
    }
#pragma unroll
    for (int i = 0; i < 6; i++) {
      int f = t + i * 256;
      int k = f / 48;
      int c = f - k * 48;
      Ws[k][c] = (c < 47) ? Wc[(size_t)(kb + k) * 47 + c] : 0.f;
    }
    __syncthreads();
#pragma unroll 4
    for (int k = 0; k < 32; k++) {
      float4 w0 = *(const float4*)&Ws[k][tc * 12];
      float4 w1 = *(const float4*)&Ws[k][tc * 12 + 4];
      float4 w2 = *(const float4*)&Ws[k][tc * 12 + 8];
      float a0 = hs[tm][k];
      float a1 = hs[tm + 64][k];
      float a2 = hs[tm + 128][k];
      float a3 = hs[tm + 192][k];
      float a[4] = {a0, a1, a2, a3};
#pragma unroll
      for (int g = 0; g < 4; g++) {
        acc[g][0] = fmaf(a[g], w0.x, acc[g][0]);
        acc[g][1] = fmaf(a[g], w0.y, acc[g][1]);
        acc[g][2] = fmaf(a[g], w0.z, acc[g][2]);
        acc[g][3] = fmaf(a[g], w0.w, acc[g][3]);
        acc[g][4] = fmaf(a[g], w1.x, acc[g][4]);
        acc[g][5] = fmaf(a[g], w1.y, acc[g][5]);
        acc[g][6] = fmaf(a[g], w1.z, acc[g][6]);
        acc[g][7] = fmaf(a[g], w1.w, acc[g][7]);
        acc[g][8] = fmaf(a[g], w2.x, acc[g][8]);
        acc[g][9] = fmaf(a[g], w2.y, acc[g][9]);
        acc[g][10] = fmaf(a[g], w2.z, acc[g][10]);
        acc[g][11] = fmaf(a[g], w2.w, acc[g][11]);
      }
    }
    __syncthreads();
  }
#pragma unroll
  for (int g = 0; g < 4; g++) {
    int r = row0 + tm + 64 * g;
    if (r < N) {
#pragma unroll
      for (int j = 0; j < 12; j++) {
        int c = tc * 12 + j;
        if (c < 47) out[(size_t)r * 47 + c] = acc[g][j] + bs[c];
      }
    }
  }
}

// ---------------- launch ----------------

extern "C" void kernel_launch(void* const* d_in, const int* in_sizes, int n_in,
                              void* d_out, int out_size, void* d_ws, size_t ws_size,
                              hipStream_t stream) {
  const float* x  = (const float*)d_in[0];
  const int* edges = (const int*)d_in[1];
  const float* W0 = (const float*)d_in[2];
  const float* b0 = (const float*)d_in[3];
  const float* W1 = (const float*)d_in[4];
  const float* b1 = (const float*)d_in[5];
  const float* Wc = (const float*)d_in[6];
  const float* bc = (const float*)d_in[7];
  float* out = (float*)d_out;

  int N = in_sizes[0] / 128;
  int E = in_sizes[1] / 2;
  const int* src = edges;
  const int* dst = edges + E;

  int NB = (N + ((1 << BSHIFT) - 1)) >> BSHIFT;
  int src_bits = 0;
  while ((1 << src_bits) < N) src_bits++;
  int per_blk = (E + PB - 1) / PB;

  char* base = (char*)d_ws;
  size_t off = 0;
  auto alloc = [&](size_t bytes) -> void* {
    void* p = base + off;
    off += (bytes + 255) & ~(size_t)255;
    return p;
  };
  float* c_src = (float*)alloc((size_t)N * 4);
  float* c_dst = (float*)alloc((size_t)N * 4);
  int* deg_out = (int*)alloc((size_t)N * 4);
  int* row_ptr = (int*)alloc((size_t)(N + 1) * 4);
  int* col_idx = (int*)alloc((size_t)E * 4);
  __half* h0h = (__half*)alloc((size_t)N * 128 * 2);   // GEMM outputs (fp16, 25.6 MB)
  float* h1 = (float*)alloc((size_t)N * 128 * 4);      // aggregate outputs (fp32)

  // build-time scratch carved out of h1 (dead until first k_aggregate writes h1)
  char* hb = (char*)h1;
  unsigned* ebuf = (unsigned*)hb;            hb += (size_t)E * 4;
  int* cntT = (int*)hb;                      hb += (size_t)NB * PB * 4;
  int* offsT = (int*)hb;                     hb += (size_t)NB * PB * 4;
  int* total = (int*)hb;                     hb += (size_t)NB * 4;
  int* bbase = (int*)hb;                     hb += (size_t)(NB + 1) * 4;

  hipMemsetAsync(deg_out, 0, (size_t)N * 4, stream);
  k_histo<<<1024, 256, 0, stream>>>(src, E, deg_out);
  k_coeffs_src<<<(N + 255) / 256, 256, 0, stream>>>(deg_out, c_src, N);

  k_count<<<PB, 256, 0, stream>>>(dst, E, per_blk, NB, cntT);
  k_scanblk<<<NB, 256, 0, stream>>>(cntT, offsT, total);
  k_scantot<<<1, 512, 0, stream>>>(total, NB, E, bbase, row_ptr, N);
  k_partition<<<PB, 256, 0, stream>>>(src, dst, E, per_blk, NB, offsT, bbase, ebuf, src_bits);
  k_finalize<<<NB, 256, 0, stream>>>(ebuf, bbase, N, src_bits, row_ptr, c_dst, col_idx);

  int strips = (N + 127) / 128;
  int gblocks = (strips + 1) / 2;
  k_gemm_mfma<<<gblocks, 256, 0, stream>>>(x, W0, c_src, h0h, N);
  k_aggregate_h<<<(N + 3) / 4, 256, 0, stream>>>(h0h, row_ptr, col_idx, c_dst, b0, h1, N);
  k_gemm_mfma<<<gblocks, 256, 0, stream>>>(h1, W1, c_src, h0h, N);
  k_aggregate_h<<<(N + 3) / 4, 256, 0, stream>>>(h0h, row_ptr, col_idx, c_dst, b1, h1, N);
  k_classifier<<<(N + 255) / 256, 256, 0, stream>>>(h1, Wc, bc, out, N);
}

// Round 9
// 409.403 us; speedup vs baseline: 2.0614x; 1.0193x over previous
//
#include <hip/hip_runtime.h>
#include <hip/hip_fp16.h>

// GCN: h0 = relu(c_dst ⊙ Agg(c_src ⊙ x @ W0) + b0); h1 = same with W1; out = h1 @ Wc + bc
// R8 (= R7 + compile fix): aggregate output stored fp16; col_idx holds byte offsets;
// GEMM templated on A dtype (fp32 layer 1, fp16 layer 2); classifier reads fp16 h.

#define PB 256          // partition blocks
#define BSHIFT 8        // bucket = dst >> 8 (256 nodes/bucket)

typedef _Float16 f16x8 __attribute__((ext_vector_type(8)));
typedef float f32x4 __attribute__((ext_vector_type(4)));

// ---------------- out-degree histogram (for c_src) ----------------

__global__ __launch_bounds__(256) void k_histo(const int* __restrict__ src, int E, int* __restrict__ dout) {
  int stride = gridDim.x * blockDim.x;
  for (int e = blockIdx.x * blockDim.x + threadIdx.x; e < E; e += stride)
    atomicAdd(&dout[src[e]], 1);
}

__global__ __launch_bounds__(256) void k_coeffs_src(const int* __restrict__ dout, float* __restrict__ c_src, int N) {
  int i = blockIdx.x * blockDim.x + threadIdx.x;
  if (i < N) c_src[i] = rsqrtf((float)max(dout[i], 1));
}

// ---------------- Phase A: bucket counts ----------------

__global__ __launch_bounds__(256) void k_count(const int* __restrict__ dst, int E, int per_blk, int NB,
                                               int* __restrict__ cntT) {
  __shared__ int cnt[512];
  for (int i = threadIdx.x; i < NB; i += 256) cnt[i] = 0;
  __syncthreads();
  int e0 = blockIdx.x * per_blk, e1 = min(E, e0 + per_blk);
  for (int e = e0 + threadIdx.x; e < e1; e += 256) atomicAdd(&cnt[dst[e] >> BSHIFT], 1);
  __syncthreads();
  for (int i = threadIdx.x; i < NB; i += 256) cntT[i * PB + blockIdx.x] = cnt[i];
}

__global__ __launch_bounds__(256) void k_scanblk(const int* __restrict__ cntT, int* __restrict__ offsT,
                                                 int* __restrict__ total) {
  __shared__ int s[256];
  int b = blockIdx.x, t = threadIdx.x;
  int v = cntT[b * PB + t];
  s[t] = v;
  __syncthreads();
  for (int off = 1; off < 256; off <<= 1) {
    int x = (t >= off) ? s[t - off] : 0;
    __syncthreads();
    s[t] += x;
    __syncthreads();
  }
  offsT[b * PB + t] = s[t] - v;
  if (t == 255) total[b] = s[255];
}

__global__ __launch_bounds__(512) void k_scantot(const int* __restrict__ total, int NB, int E,
                                                 int* __restrict__ bbase, int* __restrict__ row_ptr, int N) {
  __shared__ int s[512];
  int t = threadIdx.x;
  int v = (t < NB) ? total[t] : 0;
  s[t] = v;
  __syncthreads();
  for (int off = 1; off < 512; off <<= 1) {
    int x = (t >= off) ? s[t - off] : 0;
    __syncthreads();
    s[t] += x;
    __syncthreads();
  }
  if (t < NB) bbase[t] = s[t] - v;
  if (t == 0) { bbase[NB] = E; row_ptr[N] = E; }
}

// ---------------- Phase A: partition scatter ----------------

__global__ __launch_bounds__(256) void k_partition(const int* __restrict__ src, const int* __restrict__ dst,
                                                   int E, int per_blk, int NB,
                                                   const int* __restrict__ offsT, const int* __restrict__ bbase,
                                                   unsigned* __restrict__ ebuf, int src_bits) {
  __shared__ int cur[512];
  for (int i = threadIdx.x; i < NB; i += 256) cur[i] = bbase[i] + offsT[i * PB + blockIdx.x];
  __syncthreads();
  int e0 = blockIdx.x * per_blk, e1 = min(E, e0 + per_blk);
  for (int e = e0 + threadIdx.x; e < e1; e += 256) {
    int d = dst[e], s = src[e];
    int pos = atomicAdd(&cur[d >> BSHIFT], 1);
    ebuf[pos] = ((unsigned)(d & ((1 << BSHIFT) - 1)) << src_bits) | (unsigned)s;
  }
}

// ---------------- Phase B: per-bucket finalize -> row_ptr, c_dst, col_idx (BYTE offsets) ----------------

__global__ __launch_bounds__(256) void k_finalize(const unsigned* __restrict__ ebuf, const int* __restrict__ bbase,
                                                  int N, int src_bits, int* __restrict__ row_ptr,
                                                  float* __restrict__ c_dst, int* __restrict__ col_idx) {
  __shared__ int cnt[256];
  __shared__ int s[256];
  __shared__ int cur[256];
  int b = blockIdx.x, t = threadIdx.x;
  int r0 = bbase[b], r1 = bbase[b + 1];
  cnt[t] = 0;
  __syncthreads();
  for (int i = r0 + t; i < r1; i += 256) atomicAdd(&cnt[ebuf[i] >> src_bits], 1);
  __syncthreads();
  int v = cnt[t];
  s[t] = v;
  __syncthreads();
  for (int off = 1; off < 256; off <<= 1) {
    int x = (t >= off) ? s[t - off] : 0;
    __syncthreads();
    s[t] += x;
    __syncthreads();
  }
  int ex = s[t] - v;
  cur[t] = ex;
  int node = (b << BSHIFT) + t;
  if (node < N) {
    row_ptr[node] = r0 + ex;
    c_dst[node] = rsqrtf((float)max(v, 1));
  }
  __syncthreads();
  unsigned smask = (1u << src_bits) - 1u;
  for (int i = r0 + t; i < r1; i += 256) {
    unsigned e = ebuf[i];
    int pos = r0 + atomicAdd(&cur[e >> src_bits], 1);
    col_idx[pos] = (int)((e & smask) << 8);   // byte offset into fp16 h rows (256 B/row)
  }
}

// ---------------- MFMA GEMM: out[m][n] = (sum_k A[m][k]*sc[m]*W[k][n]) -> fp16 ----------------
// Block stages W once (Wt[n][k] fp16, stride 136), computes 2 strips of 128 rows.
// mfma(A-op = Wt tile, B-op = A rows): lane holds m=m0+li, n = nt*16+q*4+reg -> 8B stores.

__device__ __forceinline__ f16x8 load_af(const float* arow, int off, float csc) {
  float4 a0 = *(const float4*)(arow + off);
  float4 a1 = *(const float4*)(arow + off + 4);
  f16x8 v;
  v[0] = (_Float16)(a0.x * csc);
  v[1] = (_Float16)(a0.y * csc);
  v[2] = (_Float16)(a0.z * csc);
  v[3] = (_Float16)(a0.w * csc);
  v[4] = (_Float16)(a1.x * csc);
  v[5] = (_Float16)(a1.y * csc);
  v[6] = (_Float16)(a1.z * csc);
  v[7] = (_Float16)(a1.w * csc);
  return v;
}

__device__ __forceinline__ f16x8 load_af(const __half* arow, int off, float csc) {
  f16x8 v = *(const f16x8*)(arow + off);
  _Float16 c = (_Float16)csc;
#pragma unroll
  for (int j = 0; j < 8; j++) v[j] = v[j] * c;
  return v;
}

template <typename AT>
__global__ __launch_bounds__(256) void k_gemm_mfma(const AT* __restrict__ A, const float* __restrict__ W,
                                                   const float* __restrict__ scale, __half* __restrict__ out, int N) {
  __shared__ _Float16 Wt[128][136];
  int t = threadIdx.x;
  {
    int nlow = t & 15;
    int kplow = t >> 4;
#pragma unroll
    for (int j = 0; j < 32; j++) {
      int n = nlow + 16 * (j & 7);
      int kp = kplow + 16 * (j >> 3);
      float w0 = W[(size_t)(2 * kp) * 128 + n];
      float w1 = W[(size_t)(2 * kp + 1) * 128 + n];
      __half2 h2 = __floats2half2_rn(w0, w1);
      *(__half2*)&Wt[n][2 * kp] = h2;
    }
  }
  __syncthreads();

  int wave = t >> 6;
  int lane = t & 63;
  int li = lane & 15;
  int q = lane >> 4;

#pragma unroll
  for (int s2 = 0; s2 < 2; s2++) {
    int m0 = (blockIdx.x * 2 + s2) * 128 + wave * 32;
    if (m0 >= N) break;

    int mrow[2];
    float csc[2];
    bool mok[2];
    const AT* arow[2];
#pragma unroll
    for (int s = 0; s < 2; s++) {
      mrow[s] = m0 + s * 16 + li;
      mok[s] = mrow[s] < N;
      csc[s] = mok[s] ? scale[mrow[s]] : 0.f;
      arow[s] = A + (size_t)(mok[s] ? mrow[s] : 0) * 128;
    }

    f32x4 acc[2][8];
#pragma unroll
    for (int s = 0; s < 2; s++)
#pragma unroll
      for (int nt = 0; nt < 8; nt++) acc[s][nt] = (f32x4){0.f, 0.f, 0.f, 0.f};

#pragma unroll
    for (int kc = 0; kc < 128; kc += 32) {
      f16x8 af[2];
#pragma unroll
      for (int s = 0; s < 2; s++) af[s] = load_af(arow[s], kc + q * 8, csc[s]);
#pragma unroll
      for (int nt = 0; nt < 8; nt++) {
        f16x8 wf = *(const f16x8*)&Wt[nt * 16 + li][kc + q * 8];
        acc[0][nt] = __builtin_amdgcn_mfma_f32_16x16x32_f16(wf, af[0], acc[0][nt], 0, 0, 0);
        acc[1][nt] = __builtin_amdgcn_mfma_f32_16x16x32_f16(wf, af[1], acc[1][nt], 0, 0, 0);
      }
    }

#pragma unroll
    for (int s = 0; s < 2; s++) {
      if (!mok[s]) continue;
      size_t rb = (size_t)mrow[s] * 128;
#pragma unroll
      for (int nt = 0; nt < 8; nt++) {
        __half2 p0 = __floats2half2_rn(acc[s][nt][0], acc[s][nt][1]);
        __half2 p1 = __floats2half2_rn(acc[s][nt][2], acc[s][nt][3]);
        uint2 qv;
        qv.x = *(unsigned*)&p0;
        qv.y = *(unsigned*)&p1;
        *(uint2*)&out[rb + nt * 16 + q * 4] = qv;
      }
    }
  }
}

// ---------------- Sparse aggregation: fp16 rows in, fp16 out ----------------
// Wave per node; half-waves take contiguous sub-ranges; unroll 8 edges/half with
// fp16 pairwise pre-add before fp32 accumulate. col_idx = byte offsets.

__device__ __forceinline__ void acc_pair(float4& a, uint2 qa, uint2 qb) {
  __half2 s0 = __hadd2(*(__half2*)&qa.x, *(__half2*)&qb.x);
  __half2 s1 = __hadd2(*(__half2*)&qa.y, *(__half2*)&qb.y);
  float2 f0 = __half22float2(s0);
  float2 f1 = __half22float2(s1);
  a.x += f0.x; a.y += f0.y; a.z += f1.x; a.w += f1.y;
}

__device__ __forceinline__ void acc_one(float4& a, uint2 q) {
  float2 f0 = __half22float2(*(__half2*)&q.x);
  float2 f1 = __half22float2(*(__half2*)&q.y);
  a.x += f0.x; a.y += f0.y; a.z += f1.x; a.w += f1.y;
}

__global__ __launch_bounds__(256) void k_aggregate_h(const __half* __restrict__ hin, const int* __restrict__ rp,
                                                     const int* __restrict__ ci, const float* __restrict__ c_dst,
                                                     const float* __restrict__ bias, __half* __restrict__ hout, int N) {
  int v = blockIdx.x * 4 + (threadIdx.x >> 6);
  if (v >= N) return;
  int half_id = (threadIdx.x >> 5) & 1;
  int f4 = (threadIdx.x & 31) * 4;
  const char* hb = (const char*)hin + f4 * 2;
  int p0 = rp[v], pe = rp[v + 1];
  int mid = p0 + ((pe - p0 + 1) >> 1);
  int p = half_id ? mid : p0;
  int pend = half_id ? pe : mid;
  float4 a0 = make_float4(0.f, 0.f, 0.f, 0.f);
  float4 a1 = make_float4(0.f, 0.f, 0.f, 0.f);
  float4 a2 = make_float4(0.f, 0.f, 0.f, 0.f);
  float4 a3 = make_float4(0.f, 0.f, 0.f, 0.f);
  for (; p + 7 < pend; p += 8) {
    int u0 = ci[p];
    int u1 = ci[p + 1];
    int u2 = ci[p + 2];
    int u3 = ci[p + 3];
    int u4 = ci[p + 4];
    int u5 = ci[p + 5];
    int u6 = ci[p + 6];
    int u7 = ci[p + 7];
    uint2 q0 = *(const uint2*)(hb + (size_t)(unsigned)u0);
    uint2 q1 = *(const uint2*)(hb + (size_t)(unsigned)u1);
    uint2 q2 = *(const uint2*)(hb + (size_t)(unsigned)u2);
    uint2 q3 = *(const uint2*)(hb + (size_t)(unsigned)u3);
    uint2 q4 = *(const uint2*)(hb + (size_t)(unsigned)u4);
    uint2 q5 = *(const uint2*)(hb + (size_t)(unsigned)u5);
    uint2 q6 = *(const uint2*)(hb + (size_t)(unsigned)u6);
    uint2 q7 = *(const uint2*)(hb + (size_t)(unsigned)u7);
    acc_pair(a0, q0, q1);
    acc_pair(a1, q2, q3);
    acc_pair(a2, q4, q5);
    acc_pair(a3, q6, q7);
  }
  for (; p + 1 < pend; p += 2) {
    int u0 = ci[p];
    int u1 = ci[p + 1];
    uint2 q0 = *(const uint2*)(hb + (size_t)(unsigned)u0);
    uint2 q1 = *(const uint2*)(hb + (size_t)(unsigned)u1);
    acc_pair(a0, q0, q1);
  }
  if (p < pend) {
    uint2 q = *(const uint2*)(hb + (size_t)(unsigned)ci[p]);
    acc_one(a0, q);
  }
  a0.x += a1.x; a0.y += a1.y; a0.z += a1.z; a0.w += a1.w;
  a2.x += a3.x; a2.y += a3.y; a2.z += a3.z; a2.w += a3.w;
  a0.x += a2.x; a0.y += a2.y; a0.z += a2.z; a0.w += a2.w;
  a0.x += __shfl_xor(a0.x, 32);
  a0.y += __shfl_xor(a0.y, 32);
  a0.z += __shfl_xor(a0.z, 32);
  a0.w += __shfl_xor(a0.w, 32);
  if (half_id == 0) {
    float cd = c_dst[v];
    float4 b = *(const float4*)&bias[f4];
    float4 o;
    o.x = fmaxf(fmaf(a0.x, cd, b.x), 0.f);
    o.y = fmaxf(fmaf(a0.y, cd, b.y), 0.f);
    o.z = fmaxf(fmaf(a0.z, cd, b.z), 0.f);
    o.w = fmaxf(fmaf(a0.w, cd, b.w), 0.f);
    __half2 p0h = __floats2half2_rn(o.x, o.y);
    __half2 p1h = __floats2half2_rn(o.z, o.w);
    uint2 qv;
    qv.x = *(unsigned*)&p0h;
    qv.y = *(unsigned*)&p1h;
    *(uint2*)&hout[(size_t)v * 128 + f4] = qv;
  }
}

// ---------------- Classifier: out[N,47] = h(fp16) @ Wc + bc, register-tiled ----------------

__global__ __launch_bounds__(256) void k_classifier(const __half* __restrict__ h, const float* __restrict__ Wc,
                                                    const float* __restrict__ bc, float* __restrict__ out, int N) {
  __shared__ float hs[256][33];
  __shared__ float Ws[32][48];
  __shared__ float bs[48];
  int t = threadIdx.x;
  int row0 = blockIdx.x * 256;
  int tc = t & 3;
  int tm = t >> 2;
  if (t < 47) bs[t] = bc[t];
  if (t == 255) bs[47] = 0.f;

  float acc[4][12];
#pragma unroll
  for (int g = 0; g < 4; g++)
#pragma unroll
    for (int j = 0; j < 12; j++) acc[g][j] = 0.f;

  for (int kb = 0; kb < 128; kb += 32) {
#pragma unroll
    for (int i = 0; i < 4; i++) {
      int f = t + i * 256;         // 1024 slots-of-8 of 256x32 halfs
      int r = f >> 2;
      int c8 = (f & 3) * 8;
      int g = row0 + r;
      f16x8 v;
      if (g < N) v = *(const f16x8*)&h[(size_t)g * 128 + kb + c8];
      else {
#pragma unroll
        for (int j = 0; j < 8; j++) v[j] = (_Float16)0.f;
      }
#pragma unroll
      for (int j = 0; j < 8; j++) hs[r][c8 + j] = (float)v[j];
    }
#pragma unroll
    for (int i = 0; i < 6; i++) {
      int f = t + i * 256;
      int k = f / 48;
      int c = f - k * 48;
      Ws[k][c] = (c < 47) ? Wc[(size_t)(kb + k) * 47 + c] : 0.f;
    }
    __syncthreads();
#pragma unroll 4
    for (int k = 0; k < 32; k++) {
      float4 w0 = *(const float4*)&Ws[k][tc * 12];
      float4 w1 = *(const float4*)&Ws[k][tc * 12 + 4];
      float4 w2 = *(const float4*)&Ws[k][tc * 12 + 8];
      float a0 = hs[tm][k];
      float a1 = hs[tm + 64][k];
      float a2 = hs[tm + 128][k];
      float a3 = hs[tm + 192][k];
      float a[4] = {a0, a1, a2, a3};
#pragma unroll
      for (int g = 0; g < 4; g++) {
        acc[g][0] = fmaf(a[g], w0.x, acc[g][0]);
        acc[g][1] = fmaf(a[g], w0.y, acc[g][1]);
        acc[g][2] = fmaf(a[g], w0.z, acc[g][2]);
        acc[g][3] = fmaf(a[g], w0.w, acc[g][3]);
        acc[g][4] = fmaf(a[g], w1.x, acc[g][4]);
        acc[g][5] = fmaf(a[g], w1.y, acc[g][5]);
        acc[g][6] = fmaf(a[g], w1.z, acc[g][6]);
        acc[g][7] = fmaf(a[g], w1.w, acc[g][7]);
        acc[g][8] = fmaf(a[g], w2.x, acc[g][8]);
        acc[g][9] = fmaf(a[g], w2.y, acc[g][9]);
        acc[g][10] = fmaf(a[g], w2.z, acc[g][10]);
        acc[g][11] = fmaf(a[g], w2.w, acc[g][11]);
      }
    }
    __syncthreads();
  }
#pragma unroll
  for (int g = 0; g < 4; g++) {
    int r = row0 + tm + 64 * g;
    if (r < N) {
#pragma unroll
      for (int j = 0; j < 12; j++) {
        int c = tc * 12 + j;
        if (c < 47) out[(size_t)r * 47 + c] = acc[g][j] + bs[c];
      }
    }
  }
}

// ---------------- launch ----------------

extern "C" void kernel_launch(void* const* d_in, const int* in_sizes, int n_in,
                              void* d_out, int out_size, void* d_ws, size_t ws_size,
                              hipStream_t stream) {
  const float* x  = (const float*)d_in[0];
  const int* edges = (const int*)d_in[1];
  const float* W0 = (const float*)d_in[2];
  const float* b0 = (const float*)d_in[3];
  const float* W1 = (const float*)d_in[4];
  const float* b1 = (const float*)d_in[5];
  const float* Wc = (const float*)d_in[6];
  const float* bc = (const float*)d_in[7];
  float* out = (float*)d_out;

  int N = in_sizes[0] / 128;
  int E = in_sizes[1] / 2;
  const int* src = edges;
  const int* dst = edges + E;

  int NB = (N + ((1 << BSHIFT) - 1)) >> BSHIFT;
  int src_bits = 0;
  while ((1 << src_bits) < N) src_bits++;
  int per_blk = (E + PB - 1) / PB;

  char* base = (char*)d_ws;
  size_t off = 0;
  auto alloc = [&](size_t bytes) -> void* {
    void* p = base + off;
    off += (bytes + 255) & ~(size_t)255;
    return p;
  };
  float* c_src = (float*)alloc((size_t)N * 4);
  float* c_dst = (float*)alloc((size_t)N * 4);
  int* deg_out = (int*)alloc((size_t)N * 4);
  int* row_ptr = (int*)alloc((size_t)(N + 1) * 4);
  int* col_idx = (int*)alloc((size_t)E * 4);
  __half* h0h = (__half*)alloc((size_t)N * 128 * 2);   // GEMM outputs (fp16, 25.6 MB)
  __half* h1h = (__half*)alloc((size_t)N * 128 * 2);   // aggregate outputs (fp16, 25.6 MB)

  // build-time scratch carved out of h1h (dead until first k_aggregate writes it)
  char* hb = (char*)h1h;
  unsigned* ebuf = (unsigned*)hb;            hb += (size_t)E * 4;
  int* cntT = (int*)hb;                      hb += (size_t)NB * PB * 4;
  int* offsT = (int*)hb;                     hb += (size_t)NB * PB * 4;
  int* total = (int*)hb;                     hb += (size_t)NB * 4;
  int* bbase = (int*)hb;                     hb += (size_t)(NB + 1) * 4;

  hipMemsetAsync(deg_out, 0, (size_t)N * 4, stream);
  k_histo<<<1024, 256, 0, stream>>>(src, E, deg_out);
  k_coeffs_src<<<(N + 255) / 256, 256, 0, stream>>>(deg_out, c_src, N);

  k_count<<<PB, 256, 0, stream>>>(dst, E, per_blk, NB, cntT);
  k_scanblk<<<NB, 256, 0, stream>>>(cntT, offsT, total);
  k_scantot<<<1, 512, 0, stream>>>(total, NB, E, bbase, row_ptr, N);
  k_partition<<<PB, 256, 0, stream>>>(src, dst, E, per_blk, NB, offsT, bbase, ebuf, src_bits);
  k_finalize<<<NB, 256, 0, stream>>>(ebuf, bbase, N, src_bits, row_ptr, c_dst, col_idx);

  int strips = (N + 127) / 128;
  int gblocks = (strips + 1) / 2;
  k_gemm_mfma<float><<<gblocks, 256, 0, stream>>>(x, W0, c_src, h0h, N);
  k_aggregate_h<<<(N + 3) / 4, 256, 0, stream>>>(h0h, row_ptr, col_idx, c_dst, b0, h1h, N);
  k_gemm_mfma<__half><<<gblocks, 256, 0, stream>>>(h1h, W1, c_src, h0h, N);
  k_aggregate_h<<<(N + 3) / 4, 256, 0, stream>>>(h0h, row_ptr, col_idx, c_dst, b1, h1h, N);
  k_classifier<<<(N + 255) / 256, 256, 0, stream>>>(h1h, Wc, bc, out, N);
}

// Round 10
// 366.860 us; speedup vs baseline: 2.3004x; 1.1160x over previous
//
#include <hip/hip_runtime.h>
#include <hip/hip_fp16.h>

// GCN: h0 = relu(c_dst ⊙ Agg(c_src ⊙ x @ W0) + b0); h1 = same with W1; out = h1 @ Wc + bc
// R9: out-degree via bucketed two-phase (shared with dst partition) — the global-atomic
//     k_histo wrote 50 MB of dirty lines (66 µs, VALU 0.3%). Now: k_count counts both
//     src/dst buckets in LDS; k_partition scatters dstrel|src into ebuf AND srcrel bytes
//     into sbuf; k_finalize_src LDS-histograms each src bucket -> c_src. No global atomics.

#define PB 256          // partition blocks
#define BSHIFT 8        // bucket = node >> 8 (256 nodes/bucket)

typedef _Float16 f16x8 __attribute__((ext_vector_type(8)));
typedef float f32x4 __attribute__((ext_vector_type(4)));

// ---------------- Phase A: bucket counts (src and dst) ----------------

__global__ __launch_bounds__(256) void k_count(const int* __restrict__ src, const int* __restrict__ dst,
                                               int E, int per_blk, int NB,
                                               int* __restrict__ cntT, int* __restrict__ cntT2) {
  __shared__ int cnt[512];
  __shared__ int cnt2[512];
  for (int i = threadIdx.x; i < NB; i += 256) { cnt[i] = 0; cnt2[i] = 0; }
  __syncthreads();
  int e0 = blockIdx.x * per_blk, e1 = min(E, e0 + per_blk);
  for (int e = e0 + threadIdx.x; e < e1; e += 256) {
    atomicAdd(&cnt[dst[e] >> BSHIFT], 1);
    atomicAdd(&cnt2[src[e] >> BSHIFT], 1);
  }
  __syncthreads();
  for (int i = threadIdx.x; i < NB; i += 256) {
    cntT[i * PB + blockIdx.x] = cnt[i];
    cntT2[i * PB + blockIdx.x] = cnt2[i];
  }
}

// exclusive scan of each bucket's 256 per-block counts (works on concatenated tables)
__global__ __launch_bounds__(256) void k_scanblk(const int* __restrict__ cntT, int* __restrict__ offsT,
                                                 int* __restrict__ total) {
  __shared__ int s[256];
  int b = blockIdx.x, t = threadIdx.x;
  int v = cntT[b * PB + t];
  s[t] = v;
  __syncthreads();
  for (int off = 1; off < 256; off <<= 1) {
    int x = (t >= off) ? s[t - off] : 0;
    __syncthreads();
    s[t] += x;
    __syncthreads();
  }
  offsT[b * PB + t] = s[t] - v;
  if (t == 255) total[b] = s[255];
}

__global__ __launch_bounds__(512) void k_scantot(const int* __restrict__ total, int NB, int E,
                                                 int* __restrict__ bbase, int* __restrict__ row_ptr, int N) {
  __shared__ int s[512];
  int t = threadIdx.x;
  int v = (t < NB) ? total[t] : 0;
  s[t] = v;
  __syncthreads();
  for (int off = 1; off < 512; off <<= 1) {
    int x = (t >= off) ? s[t - off] : 0;
    __syncthreads();
    s[t] += x;
    __syncthreads();
  }
  if (t < NB) bbase[t] = s[t] - v;
  if (t == 0) {
    bbase[NB] = E;
    if (row_ptr) row_ptr[N] = E;
  }
}

// ---------------- Phase A: partition scatter (dst-sorted ebuf + src-bucketed srcrel bytes) ----------------

__global__ __launch_bounds__(256) void k_partition(const int* __restrict__ src, const int* __restrict__ dst,
                                                   int E, int per_blk, int NB,
                                                   const int* __restrict__ offsT, const int* __restrict__ bbase,
                                                   const int* __restrict__ offsT2, const int* __restrict__ sbase,
                                                   unsigned* __restrict__ ebuf, unsigned char* __restrict__ sbuf,
                                                   int src_bits) {
  __shared__ int cur[512];
  __shared__ int cur2[512];
  for (int i = threadIdx.x; i < NB; i += 256) {
    cur[i] = bbase[i] + offsT[i * PB + blockIdx.x];
    cur2[i] = sbase[i] + offsT2[i * PB + blockIdx.x];
  }
  __syncthreads();
  int e0 = blockIdx.x * per_blk, e1 = min(E, e0 + per_blk);
  for (int e = e0 + threadIdx.x; e < e1; e += 256) {
    int d = dst[e], s = src[e];
    int pos = atomicAdd(&cur[d >> BSHIFT], 1);
    ebuf[pos] = ((unsigned)(d & ((1 << BSHIFT) - 1)) << src_bits) | (unsigned)s;
    int pos2 = atomicAdd(&cur2[s >> BSHIFT], 1);
    sbuf[pos2] = (unsigned char)(s & ((1 << BSHIFT) - 1));
  }
}

// ---------------- Phase B: per-dst-bucket finalize -> row_ptr, c_dst, col_idx (BYTE offsets) ----------------

__global__ __launch_bounds__(256) void k_finalize(const unsigned* __restrict__ ebuf, const int* __restrict__ bbase,
                                                  int N, int src_bits, int* __restrict__ row_ptr,
                                                  float* __restrict__ c_dst, int* __restrict__ col_idx) {
  __shared__ int cnt[256];
  __shared__ int s[256];
  __shared__ int cur[256];
  int b = blockIdx.x, t = threadIdx.x;
  int r0 = bbase[b], r1 = bbase[b + 1];
  cnt[t] = 0;
  __syncthreads();
  for (int i = r0 + t; i < r1; i += 256) atomicAdd(&cnt[ebuf[i] >> src_bits], 1);
  __syncthreads();
  int v = cnt[t];
  s[t] = v;
  __syncthreads();
  for (int off = 1; off < 256; off <<= 1) {
    int x = (t >= off) ? s[t - off] : 0;
    __syncthreads();
    s[t] += x;
    __syncthreads();
  }
  int ex = s[t] - v;
  cur[t] = ex;
  int node = (b << BSHIFT) + t;
  if (node < N) {
    row_ptr[node] = r0 + ex;
    c_dst[node] = rsqrtf((float)max(v, 1));
  }
  __syncthreads();
  unsigned smask = (1u << src_bits) - 1u;
  for (int i = r0 + t; i < r1; i += 256) {
    unsigned e = ebuf[i];
    int pos = r0 + atomicAdd(&cur[e >> src_bits], 1);
    col_idx[pos] = (int)((e & smask) << 8);   // byte offset into fp16 h rows (256 B/row)
  }
}

// ---------------- Phase B: per-src-bucket histogram -> c_src ----------------

__global__ __launch_bounds__(256) void k_finalize_src(const unsigned char* __restrict__ sbuf,
                                                      const int* __restrict__ sbase, int N,
                                                      float* __restrict__ c_src) {
  __shared__ int cnt[256];
  int b = blockIdx.x, t = threadIdx.x;
  int r0 = sbase[b], r1 = sbase[b + 1];
  cnt[t] = 0;
  __syncthreads();
  for (int i = r0 + t; i < r1; i += 256) atomicAdd(&cnt[sbuf[i]], 1);
  __syncthreads();
  int node = (b << BSHIFT) + t;
  if (node < N) c_src[node] = rsqrtf((float)max(cnt[t], 1));
}

// ---------------- MFMA GEMM: out[m][n] = (sum_k A[m][k]*sc[m]*W[k][n]) -> fp16 ----------------

__device__ __forceinline__ f16x8 load_af(const float* arow, int off, float csc) {
  float4 a0 = *(const float4*)(arow + off);
  float4 a1 = *(const float4*)(arow + off + 4);
  f16x8 v;
  v[0] = (_Float16)(a0.x * csc);
  v[1] = (_Float16)(a0.y * csc);
  v[2] = (_Float16)(a0.z * csc);
  v[3] = (_Float16)(a0.w * csc);
  v[4] = (_Float16)(a1.x * csc);
  v[5] = (_Float16)(a1.y * csc);
  v[6] = (_Float16)(a1.z * csc);
  v[7] = (_Float16)(a1.w * csc);
  return v;
}

__device__ __forceinline__ f16x8 load_af(const __half* arow, int off, float csc) {
  f16x8 v = *(const f16x8*)(arow + off);
  _Float16 c = (_Float16)csc;
#pragma unroll
  for (int j = 0; j < 8; j++) v[j] = v[j] * c;
  return v;
}

template <typename AT>
__global__ __launch_bounds__(256) void k_gemm_mfma(const AT* __restrict__ A, const float* __restrict__ W,
                                                   const float* __restrict__ scale, __half* __restrict__ out, int N) {
  __shared__ _Float16 Wt[128][136];
  int t = threadIdx.x;
  {
    int nlow = t & 15;
    int kplow = t >> 4;
#pragma unroll
    for (int j = 0; j < 32; j++) {
      int n = nlow + 16 * (j & 7);
      int kp = kplow + 16 * (j >> 3);
      float w0 = W[(size_t)(2 * kp) * 128 + n];
      float w1 = W[(size_t)(2 * kp + 1) * 128 + n];
      __half2 h2 = __floats2half2_rn(w0, w1);
      *(__half2*)&Wt[n][2 * kp] = h2;
    }
  }
  __syncthreads();

  int wave = t >> 6;
  int lane = t & 63;
  int li = lane & 15;
  int q = lane >> 4;

#pragma unroll
  for (int s2 = 0; s2 < 2; s2++) {
    int m0 = (blockIdx.x * 2 + s2) * 128 + wave * 32;
    if (m0 >= N) break;

    int mrow[2];
    float csc[2];
    bool mok[2];
    const AT* arow[2];
#pragma unroll
    for (int s = 0; s < 2; s++) {
      mrow[s] = m0 + s * 16 + li;
      mok[s] = mrow[s] < N;
      csc[s] = mok[s] ? scale[mrow[s]] : 0.f;
      arow[s] = A + (size_t)(mok[s] ? mrow[s] : 0) * 128;
    }

    f32x4 acc[2][8];
#pragma unroll
    for (int s = 0; s < 2; s++)
#pragma unroll
      for (int nt = 0; nt < 8; nt++) acc[s][nt] = (f32x4){0.f, 0.f, 0.f, 0.f};

#pragma unroll
    for (int kc = 0; kc < 128; kc += 32) {
      f16x8 af[2];
#pragma unroll
      for (int s = 0; s < 2; s++) af[s] = load_af(arow[s], kc + q * 8, csc[s]);
#pragma unroll
      for (int nt = 0; nt < 8; nt++) {
        f16x8 wf = *(const f16x8*)&Wt[nt * 16 + li][kc + q * 8];
        acc[0][nt] = __builtin_amdgcn_mfma_f32_16x16x32_f16(wf, af[0], acc[0][nt], 0, 0, 0);
        acc[1][nt] = __builtin_amdgcn_mfma_f32_16x16x32_f16(wf, af[1], acc[1][nt], 0, 0, 0);
      }
    }

#pragma unroll
    for (int s = 0; s < 2; s++) {
      if (!mok[s]) continue;
      size_t rb = (size_t)mrow[s] * 128;
#pragma unroll
      for (int nt = 0; nt < 8; nt++) {
        __half2 p0 = __floats2half2_rn(acc[s][nt][0], acc[s][nt][1]);
        __half2 p1 = __floats2half2_rn(acc[s][nt][2], acc[s][nt][3]);
        uint2 qv;
        qv.x = *(unsigned*)&p0;
        qv.y = *(unsigned*)&p1;
        *(uint2*)&out[rb + nt * 16 + q * 4] = qv;
      }
    }
  }
}

// ---------------- Sparse aggregation: fp16 rows in, fp16 out ----------------

__device__ __forceinline__ void acc_pair(float4& a, uint2 qa, uint2 qb) {
  __half2 s0 = __hadd2(*(__half2*)&qa.x, *(__half2*)&qb.x);
  __half2 s1 = __hadd2(*(__half2*)&qa.y, *(__half2*)&qb.y);
  float2 f0 = __half22float2(s0);
  float2 f1 = __half22float2(s1);
  a.x += f0.x; a.y += f0.y; a.z += f1.x; a.w += f1.y;
}

__device__ __forceinline__ void acc_one(float4& a, uint2 q) {
  float2 f0 = __half22float2(*(__half2*)&q.x);
  float2 f1 = __half22float2(*(__half2*)&q.y);
  a.x += f0.x; a.y += f0.y; a.z += f1.x; a.w += f1.y;
}

__global__ __launch_bounds__(256) void k_aggregate_h(const __half* __restrict__ hin, const int* __restrict__ rp,
                                                     const int* __restrict__ ci, const float* __restrict__ c_dst,
                                                     const float* __restrict__ bias, __half* __restrict__ hout, int N) {
  int v = blockIdx.x * 4 + (threadIdx.x >> 6);
  if (v >= N) return;
  int half_id = (threadIdx.x >> 5) & 1;
  int f4 = (threadIdx.x & 31) * 4;
  const char* hb = (const char*)hin + f4 * 2;
  int p0 = rp[v], pe = rp[v + 1];
  int mid = p0 + ((pe - p0 + 1) >> 1);
  int p = half_id ? mid : p0;
  int pend = half_id ? pe : mid;
  float4 a0 = make_float4(0.f, 0.f, 0.f, 0.f);
  float4 a1 = make_float4(0.f, 0.f, 0.f, 0.f);
  float4 a2 = make_float4(0.f, 0.f, 0.f, 0.f);
  float4 a3 = make_float4(0.f, 0.f, 0.f, 0.f);
  for (; p + 7 < pend; p += 8) {
    int u0 = ci[p];
    int u1 = ci[p + 1];
    int u2 = ci[p + 2];
    int u3 = ci[p + 3];
    int u4 = ci[p + 4];
    int u5 = ci[p + 5];
    int u6 = ci[p + 6];
    int u7 = ci[p + 7];
    uint2 q0 = *(const uint2*)(hb + (size_t)(unsigned)u0);
    uint2 q1 = *(const uint2*)(hb + (size_t)(unsigned)u1);
    uint2 q2 = *(const uint2*)(hb + (size_t)(unsigned)u2);
    uint2 q3 = *(const uint2*)(hb + (size_t)(unsigned)u3);
    uint2 q4 = *(const uint2*)(hb + (size_t)(unsigned)u4);
    uint2 q5 = *(const uint2*)(hb + (size_t)(unsigned)u5);
    uint2 q6 = *(const uint2*)(hb + (size_t)(unsigned)u6);
    uint2 q7 = *(const uint2*)(hb + (size_t)(unsigned)u7);
    acc_pair(a0, q0, q1);
    acc_pair(a1, q2, q3);
    acc_pair(a2, q4, q5);
    acc_pair(a3, q6, q7);
  }
  for (; p + 1 < pend; p += 2) {
    int u0 = ci[p];
    int u1 = ci[p + 1];
    uint2 q0 = *(const uint2*)(hb + (size_t)(unsigned)u0);
    uint2 q1 = *(const uint2*)(hb + (size_t)(unsigned)u1);
    acc_pair(a0, q0, q1);
  }
  if (p < pend) {
    uint2 q = *(const uint2*)(hb + (size_t)(unsigned)ci[p]);
    acc_one(a0, q);
  }
  a0.x += a1.x; a0.y += a1.y; a0.z += a1.z; a0.w += a1.w;
  a2.x += a3.x; a2.y += a3.y; a2.z += a3.z; a2.w += a3.w;
  a0.x += a2.x; a0.y += a2.y; a0.z += a2.z; a0.w += a2.w;
  a0.x += __shfl_xor(a0.x, 32);
  a0.y += __shfl_xor(a0.y, 32);
  a0.z += __shfl_xor(a0.z, 32);
  a0.w += __shfl_xor(a0.w, 32);
  if (half_id == 0) {
    float cd = c_dst[v];
    float4 b = *(const float4*)&bias[f4];
    float4 o;
    o.x = fmaxf(fmaf(a0.x, cd, b.x), 0.f);
    o.y = fmaxf(fmaf(a0.y, cd, b.y), 0.f);
    o.z = fmaxf(fmaf(a0.z, cd, b.z), 0.f);
    o.w = fmaxf(fmaf(a0.w, cd, b.w), 0.f);
    __half2 p0h = __floats2half2_rn(o.x, o.y);
    __half2 p1h = __floats2half2_rn(o.z, o.w);
    uint2 qv;
    qv.x = *(unsigned*)&p0h;
    qv.y = *(unsigned*)&p1h;
    *(uint2*)&hout[(size_t)v * 128 + f4] = qv;
  }
}

// ---------------- Classifier: out[N,47] = h(fp16) @ Wc + bc, register-tiled ----------------

__global__ __launch_bounds__(256) void k_classifier(const __half* __restrict__ h, const float* __restrict__ Wc,
                                                    const float* __restrict__ bc, float* __restrict__ out, int N) {
  __shared__ float hs[256][33];
  __shared__ float Ws[32][48];
  __shared__ float bs[48];
  int t = threadIdx.x;
  int row0 = blockIdx.x * 256;
  int tc = t & 3;
  int tm = t >> 2;
  if (t < 47) bs[t] = bc[t];
  if (t == 255) bs[47] = 0.f;

  float acc[4][12];
#pragma unroll
  for (int g = 0; g < 4; g++)
#pragma unroll
    for (int j = 0; j < 12; j++) acc[g][j] = 0.f;

  for (int kb = 0; kb < 128; kb += 32) {
#pragma unroll
    for (int i = 0; i < 4; i++) {
      int f = t + i * 256;
      int r = f >> 2;
      int c8 = (f & 3) * 8;
      int g = row0 + r;
      f16x8 v;
      if (g < N) v = *(const f16x8*)&h[(size_t)g * 128 + kb + c8];
      else {
#pragma unroll
        for (int j = 0; j < 8; j++) v[j] = (_Float16)0.f;
      }
#pragma unroll
      for (int j = 0; j < 8; j++) hs[r][c8 + j] = (float)v[j];
    }
#pragma unroll
    for (int i = 0; i < 6; i++) {
      int f = t + i * 256;
      int k = f / 48;
      int c = f - k * 48;
      Ws[k][c] = (c < 47) ? Wc[(size_t)(kb + k) * 47 + c] : 0.f;
    }
    __syncthreads();
#pragma unroll 4
    for (int k = 0; k < 32; k++) {
      float4 w0 = *(const float4*)&Ws[k][tc * 12];
      float4 w1 = *(const float4*)&Ws[k][tc * 12 + 4];
      float4 w2 = *(const float4*)&Ws[k][tc * 12 + 8];
      float a0 = hs[tm][k];
      float a1 = hs[tm + 64][k];
      float a2 = hs[tm + 128][k];
      float a3 = hs[tm + 192][k];
      float a[4] = {a0, a1, a2, a3};
#pragma unroll
      for (int g = 0; g < 4; g++) {
        acc[g][0] = fmaf(a[g], w0.x, acc[g][0]);
        acc[g][1] = fmaf(a[g], w0.y, acc[g][1]);
        acc[g][2] = fmaf(a[g], w0.z, acc[g][2]);
        acc[g][3] = fmaf(a[g], w0.w, acc[g][3]);
        acc[g][4] = fmaf(a[g], w1.x, acc[g][4]);
        acc[g][5] = fmaf(a[g], w1.y, acc[g][5]);
        acc[g][6] = fmaf(a[g], w1.z, acc[g][6]);
        acc[g][7] = fmaf(a[g], w1.w, acc[g][7]);
        acc[g][8] = fmaf(a[g], w2.x, acc[g][8]);
        acc[g][9] = fmaf(a[g], w2.y, acc[g][9]);
        acc[g][10] = fmaf(a[g], w2.z, acc[g][10]);
        acc[g][11] = fmaf(a[g], w2.w, acc[g][11]);
      }
    }
    __syncthreads();
  }
#pragma unroll
  for (int g = 0; g < 4; g++) {
    int r = row0 + tm + 64 * g;
    if (r < N) {
#pragma unroll
      for (int j = 0; j < 12; j++) {
        int c = tc * 12 + j;
        if (c < 47) out[(size_t)r * 47 + c] = acc[g][j] + bs[c];
      }
    }
  }
}

// ---------------- launch ----------------

extern "C" void kernel_launch(void* const* d_in, const int* in_sizes, int n_in,
                              void* d_out, int out_size, void* d_ws, size_t ws_size,
                              hipStream_t stream) {
  const float* x  = (const float*)d_in[0];
  const int* edges = (const int*)d_in[1];
  const float* W0 = (const float*)d_in[2];
  const float* b0 = (const float*)d_in[3];
  const float* W1 = (const float*)d_in[4];
  const float* b1 = (const float*)d_in[5];
  const float* Wc = (const float*)d_in[6];
  const float* bc = (const float*)d_in[7];
  float* out = (float*)d_out;

  int N = in_sizes[0] / 128;
  int E = in_sizes[1] / 2;
  const int* src = edges;
  const int* dst = edges + E;

  int NB = (N + ((1 << BSHIFT) - 1)) >> BSHIFT;   // 391 (<=512 required)
  int src_bits = 0;
  while ((1 << src_bits) < N) src_bits++;          // 17
  int per_blk = (E + PB - 1) / PB;

  char* base = (char*)d_ws;
  size_t off = 0;
  auto alloc = [&](size_t bytes) -> void* {
    void* p = base + off;
    off += (bytes + 255) & ~(size_t)255;
    return p;
  };
  float* c_src = (float*)alloc((size_t)N * 4);
  float* c_dst = (float*)alloc((size_t)N * 4);
  int* row_ptr = (int*)alloc((size_t)(N + 1) * 4);
  int* col_idx = (int*)alloc((size_t)E * 4);
  __half* h0h = (__half*)alloc((size_t)N * 128 * 2);   // GEMM outputs (fp16, 25.6 MB)
  __half* h1h = (__half*)alloc((size_t)N * 128 * 2);   // aggregate outputs (fp16, 25.6 MB)

  // build-time scratch carved out of h1h (dead until first k_aggregate writes it)
  char* hb = (char*)h1h;
  unsigned* ebuf = (unsigned*)hb;            hb += (size_t)E * 4;
  unsigned char* sbuf = (unsigned char*)hb;  hb += ((size_t)E + 255) & ~(size_t)255;
  int* cntT = (int*)hb;                      hb += (size_t)2 * NB * PB * 4;   // [dst | src]
  int* offsT = (int*)hb;                     hb += (size_t)2 * NB * PB * 4;
  int* total = (int*)hb;                     hb += (size_t)2 * NB * 4;
  int* bbase = (int*)hb;                     hb += (size_t)(NB + 1) * 4;
  int* sbase = (int*)hb;                     hb += (size_t)(NB + 1) * 4;
  int* cntT2 = cntT + (size_t)NB * PB;
  int* offsT2 = offsT + (size_t)NB * PB;
  int* total2 = total + NB;

  k_count<<<PB, 256, 0, stream>>>(src, dst, E, per_blk, NB, cntT, cntT2);
  k_scanblk<<<2 * NB, 256, 0, stream>>>(cntT, offsT, total);
  k_scantot<<<1, 512, 0, stream>>>(total, NB, E, bbase, row_ptr, N);
  k_scantot<<<1, 512, 0, stream>>>(total2, NB, E, sbase, (int*)nullptr, N);
  k_partition<<<PB, 256, 0, stream>>>(src, dst, E, per_blk, NB, offsT, bbase, offsT2, sbase,
                                      ebuf, sbuf, src_bits);
  k_finalize<<<NB, 256, 0, stream>>>(ebuf, bbase, N, src_bits, row_ptr, c_dst, col_idx);
  k_finalize_src<<<NB, 256, 0, stream>>>(sbuf, sbase, N, c_src);

  int strips = (N + 127) / 128;
  int gblocks = (strips + 1) / 2;
  k_gemm_mfma<float><<<gblocks, 256, 0, stream>>>(x, W0, c_src, h0h, N);
  k_aggregate_h<<<(N + 3) / 4, 256, 0, stream>>>(h0h, row_ptr, col_idx, c_dst, b0, h1h, N);
  k_gemm_mfma<__half><<<gblocks, 256, 0, stream>>>(h1h, W1, c_src, h0h, N);
  k_aggregate_h<<<(N + 3) / 4, 256, 0, stream>>>(h0h, row_ptr, col_idx, c_dst, b1, h1h, N);
  k_classifier<<<(N + 255) / 256, 256, 0, stream>>>(h1h, Wc, bc, out, N);
}